// Round 4
// baseline (251.713 us; speedup 1.0000x reference)
//
#include <hip/hip_runtime.h>

typedef __bf16 bf16_t;
typedef bf16_t bf16x8 __attribute__((ext_vector_type(8)));
typedef float floatx4 __attribute__((ext_vector_type(4)));

#define L1C 512
#define L2C 512
#define BC  32
#define DC  1024
#define KTOP 256
#define NBIN 4096           // 12-bit bins: sign+exp+3 mantissa bits
#define CAP  512            // per-tile candidate slots (<=511 emitted/tile)
#define NT   16             // tiles per batch in gemm2 (4x4 of 128x128)
#define FBUF 16384          // final-stage LDS candidate buffer

__device__ __forceinline__ unsigned short f2bf(float f) {
    unsigned u = __float_as_uint(f);
    u += 0x7FFFu + ((u >> 16) & 1u);   // RNE (data has no NaNs)
    return (unsigned short)(u >> 16);
}

// async global->LDS, 16B per lane; LDS dest = wave-uniform base + lane*16
__device__ __forceinline__ void g2l16(const unsigned short* g, unsigned short* l) {
    __builtin_amdgcn_global_load_lds((const unsigned int*)g, (unsigned int*)l,
                                     16, 0, 0);
}

__device__ __forceinline__ float decode_key(unsigned k) {
    return __uint_as_float(k & 0x7FFFFFFFu);
}

#define CFENCE asm volatile("" ::: "memory")

// ---- scan: per-batch valid-row index lists for both masks + cnt zero ----
__global__ __launch_bounds__(512) void scan_kernel(
    const int* __restrict__ mask1, const int* __restrict__ mask2,
    int* __restrict__ idx1, int* __restrict__ idx2,
    unsigned* __restrict__ nv1, unsigned* __restrict__ nv2,
    unsigned* __restrict__ cnt) {
    __shared__ unsigned sc[512];
    int b = blockIdx.x, t = threadIdx.x;
    for (int which = 0; which < 2; which++) {
        const int* m = which ? mask2 : mask1;
        int* idx = which ? idx2 : idx1;
        unsigned v = (m[t * BC + b] == 0) ? 1u : 0u;
        sc[t] = v;
        __syncthreads();
        for (int off = 1; off < 512; off <<= 1) {
            unsigned x = (t >= off) ? sc[t - off] : 0u;
            __syncthreads();
            sc[t] += x;
            __syncthreads();
        }
        if (v) idx[b * 512 + sc[t] - 1] = t;
        if (t == 511) { if (which) nv2[b] = sc[511]; else nv1[b] = sc[511]; }
        __syncthreads();
    }
    if (t < NT) cnt[b * NT + t] = 0;
}

// ---- prep: compacting casts of in1/in2 (+zero pad to x64), W cast ----
__global__ __launch_bounds__(256) void prep_kernel(
    const float* __restrict__ in1, const float* __restrict__ in2,
    const float* __restrict__ W,
    const int* __restrict__ idx1, const int* __restrict__ idx2,
    const unsigned* __restrict__ nv1, const unsigned* __restrict__ nv2,
    unsigned short* __restrict__ A1c, unsigned short* __restrict__ A2c,
    unsigned short* __restrict__ Wb) {
    int r = blockIdx.x, t = threadIdx.x;
    const float* src;
    unsigned short* dst;
    if (r < 2 * 16384) {
        int which = r >> 14;            // 0: in1, 1: in2
        int rr = r & 16383;
        int b = rr >> 9, vi = rr & 511;
        unsigned nv = which ? nv2[b] : nv1[b];
        unsigned pad = (nv + 63u) & ~63u;
        if ((unsigned)vi >= pad) return;
        dst = (which ? A2c : A1c) + ((size_t)b * 512 + vi) * DC;
        if ((unsigned)vi < nv) {
            int l = (which ? idx2 : idx1)[b * 512 + vi];
            src = (which ? in2 : in1) + (size_t)(l * BC + b) * DC;
        } else {
            ushort4 z = {0, 0, 0, 0};
            reinterpret_cast<ushort4*>(dst)[t] = z;
            return;
        }
    } else {
        int r3 = r - 2 * 16384;
        src = W + (size_t)r3 * DC;
        dst = Wb + (size_t)r3 * DC;
    }
    float4 v = reinterpret_cast<const float4*>(src)[t];
    ushort4 o;
    o.x = f2bf(v.x); o.y = f2bf(v.y); o.z = f2bf(v.z); o.w = f2bf(v.w);
    reinterpret_cast<ushort4*>(dst)[t] = o;
}

// ---- GEMM1: V[b][j][d] = sum_e A2c[b][j][e] * Wb[d][e] ----
// 128x128 tile, BK=64, 512 threads (8 waves 2x4) for 16 waves/CU residency.
// Counted-vmcnt double buffer: stage next tile, s_waitcnt vmcnt(4) (current
// tile's 4 loads/thread landed), raw barrier; prefetch stays in flight.
__global__ __launch_bounds__(512) void gemm1_kernel(
    const unsigned short* __restrict__ A,    // A2c [32][512][1024]
    const unsigned short* __restrict__ Bt,   // Wb  [1024][1024]
    unsigned short* __restrict__ C,          // V   [32][512][1024]
    const unsigned* __restrict__ nv2) {
    int bi = blockIdx.x >> 2, mt = blockIdx.x & 3;
    unsigned pad2 = (nv2[bi] + 63u) & ~63u;
    if ((unsigned)(mt * 128) >= pad2) return;
    __shared__ unsigned short As0[2][128][32];   // [khalf][row][col]
    __shared__ unsigned short Bs0[2][128][32];
    __shared__ unsigned short As1[2][128][32];
    __shared__ unsigned short Bs1[2][128][32];
    int tid = threadIdx.x;
    int wave = tid >> 6, lane = tid & 63;
    int lane15 = lane & 15, quad = lane >> 4;
    int wm = wave >> 2, wn = wave & 3;           // 2 x 4 wave grid
    size_t m0 = (size_t)bi * 512 + mt * 128;
    size_t n0 = (size_t)blockIdx.y * 128;

    floatx4 zero = {0.f, 0.f, 0.f, 0.f};
    floatx4 acc[4][2];
#pragma unroll
    for (int i = 0; i < 4; i++)
#pragma unroll
        for (int j = 0; j < 2; j++) acc[i][j] = zero;

    auto stage = [&](unsigned short* la, unsigned short* lb, int k0) {
        // A: 1024 16B-units over 512 threads (2 chunks); unit idx = cid
#pragma unroll
        for (int c = 0; c < 2; c++) {
            int cid = c * 512 + tid;
            int h = cid >> 9, row = (cid >> 2) & 127, col8 = (cid & 3) * 8;
            g2l16(&A[(m0 + row) * DC + k0 + h * 32 + col8],
                  la + (c * 512 + wave * 64) * 8);
        }
#pragma unroll
        for (int c = 0; c < 2; c++) {
            int cid = c * 512 + tid;
            int h = cid >> 9, row = (cid >> 2) & 127, col8 = (cid & 3) * 8;
            g2l16(&Bt[(n0 + row) * DC + k0 + h * 32 + col8],
                  lb + (c * 512 + wave * 64) * 8);
        }
    };

    stage(&As0[0][0][0], &Bs0[0][0][0], 0);
#pragma unroll
    for (int t = 0; t < DC / 64; t++) {
        const unsigned short* curA = (t & 1) ? &As1[0][0][0] : &As0[0][0][0];
        const unsigned short* curB = (t & 1) ? &Bs1[0][0][0] : &Bs0[0][0][0];
        if (t + 1 < DC / 64) {
            unsigned short* nxtA = (t & 1) ? &As0[0][0][0] : &As1[0][0][0];
            unsigned short* nxtB = (t & 1) ? &Bs0[0][0][0] : &Bs1[0][0][0];
            stage(nxtA, nxtB, (t + 1) * 64);
            asm volatile("s_waitcnt vmcnt(4)" ::: "memory");  // tile t landed
        } else {
            asm volatile("s_waitcnt vmcnt(0)" ::: "memory");
        }
        __builtin_amdgcn_s_barrier();
        CFENCE;
#pragma unroll
        for (int h = 0; h < 2; h++) {
            bf16x8 af[4], bfr[2];
#pragma unroll
            for (int mi = 0; mi < 4; mi++)
                af[mi] = *reinterpret_cast<const bf16x8*>(
                    curA + h * 4096 + (wm * 64 + mi * 16 + lane15) * 32 + quad * 8);
#pragma unroll
            for (int ni = 0; ni < 2; ni++)
                bfr[ni] = *reinterpret_cast<const bf16x8*>(
                    curB + h * 4096 + (wn * 32 + ni * 16 + lane15) * 32 + quad * 8);
#pragma unroll
            for (int mi = 0; mi < 4; mi++)
#pragma unroll
                for (int ni = 0; ni < 2; ni++)
                    acc[mi][ni] = __builtin_amdgcn_mfma_f32_16x16x32_bf16(
                        af[mi], bfr[ni], acc[mi][ni], 0, 0, 0);
        }
        if (t + 1 < DC / 64) {
            CFENCE;
            __builtin_amdgcn_s_barrier();   // reads of cur done before overwrite
            CFENCE;
        }
    }
#pragma unroll
    for (int mi = 0; mi < 4; mi++)
#pragma unroll
        for (int ni = 0; ni < 2; ni++)
#pragma unroll
            for (int r = 0; r < 4; r++) {
                size_t row = m0 + wm * 64 + mi * 16 + quad * 4 + r;
                size_t col = n0 + wn * 32 + ni * 16 + lane15;
                C[row * DC + col] = f2bf(acc[mi][ni][r]);
            }
}

// ---- GEMM2: 128x128 tiles (NT=16/batch), counted-vmcnt double buffer;
//      GEMM LDS reused for histogram after K-loop; relu+bias; top-k cands ----
__global__ __launch_bounds__(256) void gemm2_kernel(
    const unsigned short* __restrict__ A1c,  // [32][512][1024]
    const unsigned short* __restrict__ V,    // [32][512][1024]
    const unsigned* __restrict__ nv1, const unsigned* __restrict__ nv2,
    const float* __restrict__ bptr,
    unsigned* __restrict__ cand,             // [32*NT][CAP]
    unsigned* __restrict__ cnt) {            // [32*NT]
    // XCD swizzle: same xcd -> same batch group
    int L = blockIdx.x;                      // [0,512)
    int xcd = L & 7, idx = L >> 3;           // 64 per xcd
    int tile = idx & 15, chunk = idx >> 4;   // chunk in [0,4)
    int b = (chunk << 3) + xcd;
    int tx = tile & 3, ty = tile >> 2;
    int m0 = ty * 128, n0 = tx * 128;
    int gblk = b * NT + tile;
    int tid = threadIdx.x;
    unsigned nv1v = nv1[b], nv2v = nv2[b];
    unsigned pad1 = (nv1v + 63u) & ~63u, pad2 = (nv2v + 63u) & ~63u;
    if ((unsigned)m0 >= pad1 || (unsigned)n0 >= pad2) {
        if (tid == 0) cnt[gblk] = 0;
        return;
    }
    // 64 KB shared: GEMM staging during K-loop, histogram after
    __shared__ unsigned smem_u[16384];
    unsigned short* As0 = (unsigned short*)smem_u;          // [2][128][32]
    unsigned short* Bs0 = As0 + 8192;
    unsigned short* As1 = As0 + 16384;
    unsigned short* Bs1 = As0 + 24576;
    unsigned* lh = smem_u;                                  // [NBIN] (16 KB)
    __shared__ unsigned csum[256];
    __shared__ unsigned sel_c, sel_a, tsh, lcnt, zeq;
    int wave = tid >> 6, lane = tid & 63;
    int lane15 = lane & 15, quad = lane >> 4;
    int wm = wave >> 1, wn = wave & 1;       // 2 x 2 wave grid
    const unsigned short* Ab = A1c + (size_t)b * 512 * DC;
    const unsigned short* Bb = V + (size_t)b * 512 * DC;

    floatx4 zero = {0.f, 0.f, 0.f, 0.f};
    floatx4 acc[4][4];
#pragma unroll
    for (int i = 0; i < 4; i++)
#pragma unroll
        for (int j = 0; j < 4; j++) acc[i][j] = zero;

    auto stage = [&](unsigned short* la, unsigned short* lb, int k0) {
#pragma unroll
        for (int c = 0; c < 4; c++) {
            int cid = c * 256 + tid;
            int h = cid >> 9, row = (cid >> 2) & 127, col8 = (cid & 3) * 8;
            g2l16(&Ab[(size_t)(m0 + row) * DC + k0 + h * 32 + col8],
                  la + (c * 256 + wave * 64) * 8);
        }
#pragma unroll
        for (int c = 0; c < 4; c++) {
            int cid = c * 256 + tid;
            int h = cid >> 9, row = (cid >> 2) & 127, col8 = (cid & 3) * 8;
            g2l16(&Bb[(size_t)(n0 + row) * DC + k0 + h * 32 + col8],
                  lb + (c * 256 + wave * 64) * 8);
        }
    };

    stage(As0, Bs0, 0);
#pragma unroll
    for (int t = 0; t < DC / 64; t++) {
        const unsigned short* curA = (t & 1) ? As1 : As0;
        const unsigned short* curB = (t & 1) ? Bs1 : Bs0;
        if (t + 1 < DC / 64) {
            unsigned short* nxtA = (t & 1) ? As0 : As1;
            unsigned short* nxtB = (t & 1) ? Bs0 : Bs1;
            stage(nxtA, nxtB, (t + 1) * 64);
            asm volatile("s_waitcnt vmcnt(8)" ::: "memory");  // tile t landed
        } else {
            asm volatile("s_waitcnt vmcnt(0)" ::: "memory");
        }
        __builtin_amdgcn_s_barrier();
        CFENCE;
#pragma unroll
        for (int h = 0; h < 2; h++) {
            bf16x8 af[4], bfr[4];
#pragma unroll
            for (int mi = 0; mi < 4; mi++)
                af[mi] = *reinterpret_cast<const bf16x8*>(
                    curA + h * 4096 + (wm * 64 + mi * 16 + lane15) * 32 + quad * 8);
#pragma unroll
            for (int ni = 0; ni < 4; ni++)
                bfr[ni] = *reinterpret_cast<const bf16x8*>(
                    curB + h * 4096 + (wn * 64 + ni * 16 + lane15) * 32 + quad * 8);
#pragma unroll
            for (int mi = 0; mi < 4; mi++)
#pragma unroll
                for (int ni = 0; ni < 4; ni++)
                    acc[mi][ni] = __builtin_amdgcn_mfma_f32_16x16x32_bf16(
                        af[mi], bfr[ni], acc[mi][ni], 0, 0, 0);
        }
        CFENCE;
        __builtin_amdgcn_s_barrier();   // also separates LDS reuse below
        CFENCE;
    }

    // GEMM LDS now free -> histogram
    for (int i = tid; i < NBIN; i += 256) lh[i] = 0;
    if (tid == 0) { sel_c = 0xFFFFFFFFu; lcnt = 0; zeq = 0; }
    __syncthreads();

    float bias = bptr[0];
    // pass 1: 4096-bin histogram (zero scores privatized)
    unsigned zc = 0;
#pragma unroll
    for (int mi = 0; mi < 4; mi++)
#pragma unroll
        for (int ni = 0; ni < 4; ni++) {
            int jl = n0 + wn * 64 + ni * 16 + lane15;
            int v2 = (unsigned)jl < nv2v;
#pragma unroll
            for (int r = 0; r < 4; r++) {
                int il = m0 + wm * 64 + mi * 16 + quad * 4 + r;
                float s = acc[mi][ni][r] + bias;
                if (v2 && (unsigned)il < nv1v) {
                    if (s > 0.f)
                        atomicAdd(&lh[(__float_as_uint(s) | 0x80000000u) >> 20], 1u);
                    else
                        zc++;
                }
            }
        }
    if (zc) atomicAdd(&lh[2048], zc);
    __syncthreads();
    unsigned s16 = 0;
#pragma unroll
    for (int i = 0; i < 16; i++) s16 += lh[tid * 16 + i];
    csum[tid] = s16;
    __syncthreads();
    // parallel suffix scan over 256 chunks
    for (int off = 1; off < 256; off <<= 1) {
        unsigned v = (tid + off < 256) ? csum[tid + off] : 0u;
        __syncthreads();
        csum[tid] += v;
        __syncthreads();
    }
    {   // locate chunk holding the 256th (valid chunks are >=128)
        unsigned above = (tid < 255) ? csum[tid + 1] : 0u;
        if (tid >= 128 && csum[tid] >= KTOP && above < KTOP) {
            sel_c = (unsigned)tid; sel_a = above;
        }
    }
    __syncthreads();
    if (tid == 0) {
        if (sel_c == 0xFFFFFFFFu) {
            tsh = 2048u << 20;          // fewer than k valid: take all
        } else {
            unsigned cum = sel_a, bin = 2048;
            for (int bb = (int)sel_c * 16 + 15; bb >= (int)sel_c * 16; --bb) {
                unsigned hb = lh[bb];
                if (cum + hb >= KTOP) { bin = (unsigned)bb; break; }
                cum += hb;
            }
            tsh = bin << 20;
        }
    }
    __syncthreads();
    // pass 2: emit; exact-T ties gated to <= KTOP
    unsigned T = tsh;
    unsigned base = (unsigned)gblk * CAP;
#pragma unroll
    for (int mi = 0; mi < 4; mi++)
#pragma unroll
        for (int ni = 0; ni < 4; ni++) {
            int jl = n0 + wn * 64 + ni * 16 + lane15;
            int v2 = (unsigned)jl < nv2v;
#pragma unroll
            for (int r = 0; r < 4; r++) {
                int il = m0 + wm * 64 + mi * 16 + quad * 4 + r;
                float s = acc[mi][ni][r] + bias;
                s = s > 0.f ? s : 0.f;
                unsigned key = (v2 && (unsigned)il < nv1v)
                                   ? (__float_as_uint(s) | 0x80000000u) : 0u;
                if (key > T) {
                    unsigned p = atomicAdd(&lcnt, 1u);
                    if (p < CAP) cand[base + p] = key;
                } else if (key == T) {
                    unsigned z = atomicAdd(&zeq, 1u);
                    if (z < KTOP) {
                        unsigned p = atomicAdd(&lcnt, 1u);
                        if (p < CAP) cand[base + p] = key;
                    }
                }
            }
        }
    __syncthreads();
    if (tid == 0) cnt[gblk] = lcnt < CAP ? lcnt : CAP;
}

// ---- final: per batch, EXACT top-256 via 3-pass LDS radix select ----
__global__ __launch_bounds__(1024) void final_kernel(
    const unsigned* __restrict__ cand, const unsigned* __restrict__ cnt,
    float* __restrict__ out) {
    __shared__ unsigned buf[FBUF];     // 64 KB
    __shared__ unsigned h[NBIN];       // 16 KB
    __shared__ unsigned ss[256];
    __shared__ unsigned scnt_s[NT], off_s[NT];
    __shared__ unsigned ntot_s, sel_c, sel_a, B_s, R_s, mcount;
    __shared__ int have_s;
    __shared__ unsigned srt[256];
    int b = blockIdx.x, tid = threadIdx.x;
    int wv = tid >> 6, ln = tid & 63;

    if (tid < NT) {
        unsigned c = cnt[b * NT + tid];
        scnt_s[tid] = c < CAP ? c : CAP;
    }
    __syncthreads();
    if (tid == 0) {
        unsigned o = 0;
        for (int i = 0; i < NT; i++) {
            unsigned c = scnt_s[i];
            if (o + c > FBUF) c = (o < FBUF) ? FBUF - o : 0;
            scnt_s[i] = c;
            off_s[i] = o;
            o += c;
        }
        ntot_s = o;
        have_s = 1;
    }
    __syncthreads();
    // wave-parallel staging: wave wv handles segment wv (NT=16 waves)
    for (int s = wv; s < NT; s += 16) {
        unsigned c = scnt_s[s], o = off_s[s];
        const unsigned* p = cand + (size_t)(b * NT + s) * CAP;
        for (unsigned i = ln; i < c; i += 64) buf[o + i] = p[i];
    }
    __syncthreads();
    unsigned n = ntot_s;

    unsigned Kr = KTOP;
    unsigned pfx = 0;
    unsigned kth = 0;
    for (int pass = 0; pass < 3; pass++) {
        int bins = (pass < 2) ? NBIN : 256;
        int shift = (pass == 0) ? 20 : (pass == 1) ? 8 : 0;
        int nch = bins >> 4;
        for (int i = tid; i < bins; i += 1024) h[i] = 0;
        __syncthreads();
        for (unsigned i = tid; i < n; i += 1024) {
            unsigned k = buf[i];
            bool ok = (pass == 0) ||
                      (pass == 1 && (k >> 20) == pfx) ||
                      (pass == 2 && (k >> 8) == pfx);
            if (ok) atomicAdd(&h[(k >> shift) & (bins - 1)], 1u);
        }
        __syncthreads();
        if (tid < nch) {
            unsigned s = 0;
#pragma unroll
            for (int i = 0; i < 16; i++) s += h[tid * 16 + i];
            ss[tid] = s;
        }
        __syncthreads();
        for (int off = 1; off < nch; off <<= 1) {
            unsigned v = 0;
            if (tid < nch && tid + (unsigned)off < (unsigned)nch) v = ss[tid + off];
            __syncthreads();
            if (tid < nch) ss[tid] += v;
            __syncthreads();
        }
        if (pass == 0) {
            if (tid == 0) have_s = (ss[0] >= KTOP);
            __syncthreads();
            if (!have_s) break;
        }
        if (tid < nch) {
            unsigned above = (tid + 1 < (unsigned)nch) ? ss[tid + 1] : 0u;
            if (above < Kr && ss[tid] >= Kr) { sel_c = tid; sel_a = above; }
        }
        __syncthreads();
        if (tid == 0) {
            unsigned cum = sel_a;
            for (int bb = (int)sel_c * 16 + 15; bb >= (int)sel_c * 16; --bb) {
                unsigned hb = h[bb];
                if (cum + hb >= Kr) { B_s = (unsigned)bb; R_s = Kr - cum; break; }
                cum += hb;
            }
        }
        __syncthreads();
        unsigned Bv = B_s;
        Kr = R_s;
        if (pass == 0) pfx = Bv;
        else if (pass == 1) pfx = (pfx << 12) | Bv;
        else kth = (pfx << 8) | Bv;
        __syncthreads();
    }

    if (tid == 0) mcount = 0;
    __syncthreads();
    int have = have_s;
    unsigned lim = have ? kth : 0u;
    for (unsigned i = tid; i < n; i += 1024) {
        unsigned k = buf[i];
        if (k > lim) {
            unsigned p = atomicAdd(&mcount, 1u);
            if (p < 256) srt[p] = k;
        }
    }
    __syncthreads();
    unsigned m = mcount;
    if (tid < 256 && tid >= (int)m) srt[tid] = have ? kth : 0u;
    for (int k2 = 2; k2 <= 256; k2 <<= 1) {
        for (int j2 = k2 >> 1; j2 > 0; j2 >>= 1) {
            __syncthreads();
            if (tid < 256) {
                int ixj = tid ^ j2;
                if (ixj > tid) {
                    unsigned a = srt[tid], c = srt[ixj];
                    bool up = (tid & k2) == 0;
                    if (up ? (a < c) : (a > c)) { srt[tid] = c; srt[ixj] = a; }
                }
            }
        }
    }
    __syncthreads();
    if (tid < 256) {
        unsigned nval = have ? KTOP : (m < KTOP ? m : KTOP);
        float v;
        if ((unsigned)tid < nval) v = decode_key(srt[tid]);
        else v = (nval > 0) ? decode_key(srt[nval - 1]) : -__builtin_inff();
        out[b * KTOP + tid] = v;
    }
}

// ---------------- launch ----------------
extern "C" void kernel_launch(void* const* d_in, const int* in_sizes, int n_in,
                              void* d_out, int out_size, void* d_ws, size_t ws_size,
                              hipStream_t stream) {
    const float* in1   = (const float*)d_in[0];   // [512,32,1024]
    const float* in2   = (const float*)d_in[1];   // [512,32,1024]
    const int*   mask1 = (const int*)d_in[2];     // [512,32]
    const int*   mask2 = (const int*)d_in[3];     // [512,32]
    const float* W     = (const float*)d_in[4];   // [1024,1024]
    const float* bias  = (const float*)d_in[5];   // [1]
    float* out = (float*)d_out;

    char* ws = (char*)d_ws;
    size_t off = 0;
    const size_t nElem = (size_t)512 * BC * DC;
    unsigned short* A1c = (unsigned short*)(ws + off); off += nElem * 2;      // 32 MB
    unsigned short* A2c = (unsigned short*)(ws + off); off += nElem * 2;      // 32 MB
    unsigned short* Wb  = (unsigned short*)(ws + off); off += (size_t)DC * DC * 2; // 2 MB
    unsigned short* V   = (unsigned short*)(ws + off); off += nElem * 2;      // 32 MB
    unsigned* cand = (unsigned*)(ws + off); off += (size_t)BC * NT * CAP * 4; // 1 MB
    unsigned* cnt  = (unsigned*)(ws + off); off += (size_t)BC * NT * 4;
    int* idx1 = (int*)(ws + off); off += (size_t)BC * 512 * 4;
    int* idx2 = (int*)(ws + off); off += (size_t)BC * 512 * 4;
    unsigned* nv1 = (unsigned*)(ws + off); off += BC * 4;
    unsigned* nv2 = (unsigned*)(ws + off); off += BC * 4;

    scan_kernel<<<BC, 512, 0, stream>>>(mask1, mask2, idx1, idx2, nv1, nv2, cnt);
    prep_kernel<<<2 * 16384 + 1024, 256, 0, stream>>>(
        in1, in2, W, idx1, idx2, nv1, nv2, A1c, A2c, Wb);
    gemm1_kernel<<<dim3(128, 8), 512, 0, stream>>>(A2c, Wb, V, nv2);
    gemm2_kernel<<<512, 256, 0, stream>>>(A1c, V, nv1, nv2, bias, cand, cnt);
    final_kernel<<<BC, 1024, 0, stream>>>(cand, cnt, out);
}

// Round 6
// 244.006 us; speedup vs baseline: 1.0316x; 1.0316x over previous
//
#include <hip/hip_runtime.h>

typedef __bf16 bf16_t;
typedef bf16_t bf16x8 __attribute__((ext_vector_type(8)));
typedef float floatx4 __attribute__((ext_vector_type(4)));

#define L1C 512
#define L2C 512
#define BC  32
#define DC  1024
#define KTOP 256
#define NBIN 4096           // 12-bit bins: sign+exp+3 mantissa bits
#define CAP  512            // per-tile candidate slots (64x64 tile)
#define NT   64             // tiles per batch in gemm2 (8x8)
#define FBUF 16384          // final-stage LDS candidate buffer

__device__ __forceinline__ unsigned short f2bf(float f) {
    unsigned u = __float_as_uint(f);
    u += 0x7FFFu + ((u >> 16) & 1u);   // RNE (data has no NaNs)
    return (unsigned short)(u >> 16);
}

// async global->LDS, 16B per lane; LDS dest = wave-uniform base + lane*16
__device__ __forceinline__ void g2l16(const unsigned short* g, unsigned short* l) {
    __builtin_amdgcn_global_load_lds((const unsigned int*)g, (unsigned int*)l,
                                     16, 0, 0);
}

__device__ __forceinline__ float decode_key(unsigned k) {
    return __uint_as_float(k & 0x7FFFFFFFu);
}

#define CFENCE asm volatile("" ::: "memory")

// ---- scan: per-batch valid-row index lists for both masks + cnt zero ----
__global__ __launch_bounds__(512) void scan_kernel(
    const int* __restrict__ mask1, const int* __restrict__ mask2,
    int* __restrict__ idx1, int* __restrict__ idx2,
    unsigned* __restrict__ nv1, unsigned* __restrict__ nv2,
    unsigned* __restrict__ cnt) {
    __shared__ unsigned sc[512];
    int b = blockIdx.x, t = threadIdx.x;
    for (int which = 0; which < 2; which++) {
        const int* m = which ? mask2 : mask1;
        int* idx = which ? idx2 : idx1;
        unsigned v = (m[t * BC + b] == 0) ? 1u : 0u;
        sc[t] = v;
        __syncthreads();
        for (int off = 1; off < 512; off <<= 1) {
            unsigned x = (t >= off) ? sc[t - off] : 0u;
            __syncthreads();
            sc[t] += x;
            __syncthreads();
        }
        if (v) idx[b * 512 + sc[t] - 1] = t;
        if (t == 511) { if (which) nv2[b] = sc[511]; else nv1[b] = sc[511]; }
        __syncthreads();
    }
    if (t < NT) cnt[b * NT + t] = 0;
}

// ---- wl: deterministic gemm2 tile worklist (single block, no atomics) ----
__global__ __launch_bounds__(256) void wl_kernel(
    const unsigned* __restrict__ nv1, const unsigned* __restrict__ nv2,
    unsigned* __restrict__ wl, unsigned* __restrict__ wcount) {
    __shared__ unsigned t1s[BC], t2s[BC], offs[BC + 1];
    int tid = threadIdx.x;
    if (tid < BC) {
        unsigned p1 = (nv1[tid] + 63u) & ~63u, p2 = (nv2[tid] + 63u) & ~63u;
        t1s[tid] = p1 >> 6; t2s[tid] = p2 >> 6;   // tiles per dim (<=8)
    }
    __syncthreads();
    if (tid == 0) {
        unsigned o = 0;
        for (int b = 0; b < BC; b++) { offs[b] = o; o += t1s[b] * t2s[b]; }
        offs[BC] = o;
        *wcount = o;
    }
    __syncthreads();
    for (int b = 0; b < BC; b++) {
        unsigned nt = t1s[b] * t2s[b], o = offs[b], t2 = t2s[b];
        for (unsigned i = tid; i < nt; i += 256)
            wl[o + i] = ((unsigned)b << 6) | ((i / t2) << 3) | (i % t2);
    }
}

// ---- prep: compacting casts of in1/in2 (+zero pad to x64), W cast ----
__global__ __launch_bounds__(256) void prep_kernel(
    const float* __restrict__ in1, const float* __restrict__ in2,
    const float* __restrict__ W,
    const int* __restrict__ idx1, const int* __restrict__ idx2,
    const unsigned* __restrict__ nv1, const unsigned* __restrict__ nv2,
    unsigned short* __restrict__ A1c, unsigned short* __restrict__ A2c,
    unsigned short* __restrict__ Wb) {
    int r = blockIdx.x, t = threadIdx.x;
    const float* src;
    unsigned short* dst;
    if (r < 2 * 16384) {
        int which = r >> 14;            // 0: in1, 1: in2
        int rr = r & 16383;
        int b = rr >> 9, vi = rr & 511;
        unsigned nv = which ? nv2[b] : nv1[b];
        unsigned pad = (nv + 63u) & ~63u;
        if ((unsigned)vi >= pad) return;
        dst = (which ? A2c : A1c) + ((size_t)b * 512 + vi) * DC;
        if ((unsigned)vi < nv) {
            int l = (which ? idx2 : idx1)[b * 512 + vi];
            src = (which ? in2 : in1) + (size_t)(l * BC + b) * DC;
        } else {
            ushort4 z = {0, 0, 0, 0};
            reinterpret_cast<ushort4*>(dst)[t] = z;
            return;
        }
    } else {
        int r3 = r - 2 * 16384;
        src = W + (size_t)r3 * DC;
        dst = Wb + (size_t)r3 * DC;
    }
    float4 v = reinterpret_cast<const float4*>(src)[t];
    ushort4 o;
    o.x = f2bf(v.x); o.y = f2bf(v.y); o.z = f2bf(v.z); o.w = f2bf(v.w);
    reinterpret_cast<ushort4*>(dst)[t] = o;
}

// ---- GEMM1: V[b][j][d] = sum_e A2c[b][j][e] * Wb[d][e] ----
// 128x128 tile, BK=64, 512 threads (8 waves 2x4). Counted-vmcnt double
// buffer: stage next tile, s_waitcnt vmcnt(4), raw barrier.
__global__ __launch_bounds__(512) void gemm1_kernel(
    const unsigned short* __restrict__ A,    // A2c [32][512][1024]
    const unsigned short* __restrict__ Bt,   // Wb  [1024][1024]
    unsigned short* __restrict__ C,          // V   [32][512][1024]
    const unsigned* __restrict__ nv2) {
    int bi = blockIdx.x >> 2, mt = blockIdx.x & 3;
    unsigned pad2 = (nv2[bi] + 63u) & ~63u;
    if ((unsigned)(mt * 128) >= pad2) return;
    __shared__ unsigned short As0[2][128][32];   // [khalf][row][col]
    __shared__ unsigned short Bs0[2][128][32];
    __shared__ unsigned short As1[2][128][32];
    __shared__ unsigned short Bs1[2][128][32];
    int tid = threadIdx.x;
    int wave = tid >> 6, lane = tid & 63;
    int lane15 = lane & 15, quad = lane >> 4;
    int wm = wave >> 2, wn = wave & 3;           // 2 x 4 wave grid
    size_t m0 = (size_t)bi * 512 + mt * 128;
    size_t n0 = (size_t)blockIdx.y * 128;

    floatx4 zero = {0.f, 0.f, 0.f, 0.f};
    floatx4 acc[4][2];
#pragma unroll
    for (int i = 0; i < 4; i++)
#pragma unroll
        for (int j = 0; j < 2; j++) acc[i][j] = zero;

    auto stage = [&](unsigned short* la, unsigned short* lb, int k0) {
#pragma unroll
        for (int c = 0; c < 2; c++) {
            int cid = c * 512 + tid;
            int h = cid >> 9, row = (cid >> 2) & 127, col8 = (cid & 3) * 8;
            g2l16(&A[(m0 + row) * DC + k0 + h * 32 + col8],
                  la + (c * 512 + wave * 64) * 8);
        }
#pragma unroll
        for (int c = 0; c < 2; c++) {
            int cid = c * 512 + tid;
            int h = cid >> 9, row = (cid >> 2) & 127, col8 = (cid & 3) * 8;
            g2l16(&Bt[(n0 + row) * DC + k0 + h * 32 + col8],
                  lb + (c * 512 + wave * 64) * 8);
        }
    };

    stage(&As0[0][0][0], &Bs0[0][0][0], 0);
#pragma unroll
    for (int t = 0; t < DC / 64; t++) {
        const unsigned short* curA = (t & 1) ? &As1[0][0][0] : &As0[0][0][0];
        const unsigned short* curB = (t & 1) ? &Bs1[0][0][0] : &Bs0[0][0][0];
        if (t + 1 < DC / 64) {
            unsigned short* nxtA = (t & 1) ? &As0[0][0][0] : &As1[0][0][0];
            unsigned short* nxtB = (t & 1) ? &Bs0[0][0][0] : &Bs1[0][0][0];
            stage(nxtA, nxtB, (t + 1) * 64);
            asm volatile("s_waitcnt vmcnt(4)" ::: "memory");  // tile t landed
        } else {
            asm volatile("s_waitcnt vmcnt(0)" ::: "memory");
        }
        __builtin_amdgcn_s_barrier();
        CFENCE;
#pragma unroll
        for (int h = 0; h < 2; h++) {
            bf16x8 af[4], bfr[2];
#pragma unroll
            for (int mi = 0; mi < 4; mi++)
                af[mi] = *reinterpret_cast<const bf16x8*>(
                    curA + h * 4096 + (wm * 64 + mi * 16 + lane15) * 32 + quad * 8);
#pragma unroll
            for (int ni = 0; ni < 2; ni++)
                bfr[ni] = *reinterpret_cast<const bf16x8*>(
                    curB + h * 4096 + (wn * 32 + ni * 16 + lane15) * 32 + quad * 8);
#pragma unroll
            for (int mi = 0; mi < 4; mi++)
#pragma unroll
                for (int ni = 0; ni < 2; ni++)
                    acc[mi][ni] = __builtin_amdgcn_mfma_f32_16x16x32_bf16(
                        af[mi], bfr[ni], acc[mi][ni], 0, 0, 0);
        }
        if (t + 1 < DC / 64) {
            CFENCE;
            __builtin_amdgcn_s_barrier();   // reads of cur done before overwrite
            CFENCE;
        }
    }
#pragma unroll
    for (int mi = 0; mi < 4; mi++)
#pragma unroll
        for (int ni = 0; ni < 2; ni++)
#pragma unroll
            for (int r = 0; r < 4; r++) {
                size_t row = m0 + wm * 64 + mi * 16 + quad * 4 + r;
                size_t col = n0 + wn * 32 + ni * 16 + lane15;
                C[row * DC + col] = f2bf(acc[mi][ni][r]);
            }
}

// ---- GEMM2: persistent blocks over device-built 64x64 tile worklist;
//      counted-vmcnt double buffer; relu + bias; top-k candidates ----
__global__ __launch_bounds__(256) void gemm2_kernel(
    const unsigned short* __restrict__ A1c,  // [32][512][1024]
    const unsigned short* __restrict__ V,    // [32][512][1024]
    const unsigned* __restrict__ nv1, const unsigned* __restrict__ nv2,
    const float* __restrict__ bptr,
    unsigned* __restrict__ cand,             // [32*NT][CAP]
    unsigned* __restrict__ cnt,              // [32*NT]
    const unsigned* __restrict__ wl, const unsigned* __restrict__ wcount) {
    __shared__ unsigned short As0[2][64][32];   // [khalf][row][col]
    __shared__ unsigned short Bs0[2][64][32];
    __shared__ unsigned short As1[2][64][32];
    __shared__ unsigned short Bs1[2][64][32];
    __shared__ unsigned lh[NBIN];
    __shared__ unsigned csum[256];
    __shared__ unsigned sel_c, sel_a, tsh, lcnt, zeq;
    int tid = threadIdx.x;
    int wave = tid >> 6, lane = tid & 63;
    int lane15 = lane & 15, quad = lane >> 4;
    unsigned nwork = *wcount;
    float bias = bptr[0];
    // XCD-chunked order: consecutive worklist entries (same batch) stay on
    // the same XCD for L2 reuse of the batch's A/V panels.
    unsigned chunk = gridDim.x >> 3;
    unsigned w0 = (blockIdx.x & 7) * chunk + (blockIdx.x >> 3);

    for (unsigned w = w0; w < nwork; w += gridDim.x) {
        unsigned d = wl[w];
        int b = d >> 6, ty = (d >> 3) & 7, tx = d & 7;
        int m0 = ty * 64, n0 = tx * 64;
        int gblk = b * NT + ty * 8 + tx;
        unsigned nv1v = nv1[b], nv2v = nv2[b];
        const unsigned short* Ab = A1c + (size_t)b * 512 * DC;
        const unsigned short* Bb = V + (size_t)b * 512 * DC;

        for (int i = tid; i < NBIN; i += 256) lh[i] = 0;
        if (tid == 0) { sel_c = 0xFFFFFFFFu; lcnt = 0; zeq = 0; }

        floatx4 zero = {0.f, 0.f, 0.f, 0.f};
        floatx4 acc[4];
#pragma unroll
        for (int i = 0; i < 4; i++) acc[i] = zero;

        auto stage = [&](unsigned short* la, unsigned short* lb, int k0) {
#pragma unroll
            for (int c = 0; c < 2; c++) {
                int cid = c * 256 + tid;   // [0,512)
                int h = cid >> 8, row = (cid >> 2) & 63, col8 = (cid & 3) * 8;
                g2l16(&Ab[(size_t)(m0 + row) * DC + k0 + h * 32 + col8],
                      la + (c * 256 + wave * 64) * 8);
                g2l16(&Bb[(size_t)(n0 + row) * DC + k0 + h * 32 + col8],
                      lb + (c * 256 + wave * 64) * 8);
            }
        };

        stage(&As0[0][0][0], &Bs0[0][0][0], 0);
#pragma unroll
        for (int t = 0; t < DC / 64; t++) {
            const unsigned short* curA = (t & 1) ? &As1[0][0][0] : &As0[0][0][0];
            const unsigned short* curB = (t & 1) ? &Bs1[0][0][0] : &Bs0[0][0][0];
            if (t + 1 < DC / 64) {
                unsigned short* nxtA = (t & 1) ? &As0[0][0][0] : &As1[0][0][0];
                unsigned short* nxtB = (t & 1) ? &Bs0[0][0][0] : &Bs1[0][0][0];
                stage(nxtA, nxtB, (t + 1) * 64);
                asm volatile("s_waitcnt vmcnt(4)" ::: "memory");  // tile t landed
            } else {
                asm volatile("s_waitcnt vmcnt(0)" ::: "memory");
            }
            __builtin_amdgcn_s_barrier();
            CFENCE;
#pragma unroll
            for (int h = 0; h < 2; h++) {
                bf16x8 af, bfr[4];
                af = *reinterpret_cast<const bf16x8*>(
                    curA + h * 2048 + (wave * 16 + lane15) * 32 + quad * 8);
#pragma unroll
                for (int ni = 0; ni < 4; ni++)
                    bfr[ni] = *reinterpret_cast<const bf16x8*>(
                        curB + h * 2048 + (ni * 16 + lane15) * 32 + quad * 8);
#pragma unroll
                for (int ni = 0; ni < 4; ni++)
                    acc[ni] = __builtin_amdgcn_mfma_f32_16x16x32_bf16(
                        af, bfr[ni], acc[ni], 0, 0, 0);
            }
            CFENCE;
            __builtin_amdgcn_s_barrier();
            CFENCE;
        }

        // pass 1: 4096-bin histogram (zero scores privatized)
        unsigned zc = 0;
#pragma unroll
        for (int ni = 0; ni < 4; ni++) {
            int jl = n0 + ni * 16 + lane15;
            int v2 = (unsigned)jl < nv2v;
#pragma unroll
            for (int r = 0; r < 4; r++) {
                int il = m0 + wave * 16 + quad * 4 + r;
                float s = acc[ni][r] + bias;
                if (v2 && (unsigned)il < nv1v) {
                    if (s > 0.f)
                        atomicAdd(&lh[(__float_as_uint(s) | 0x80000000u) >> 20], 1u);
                    else
                        zc++;
                }
            }
        }
        if (zc) atomicAdd(&lh[2048], zc);
        __syncthreads();
        unsigned s16 = 0;
#pragma unroll
        for (int i = 0; i < 16; i++) s16 += lh[tid * 16 + i];
        csum[tid] = s16;
        __syncthreads();
        // parallel suffix scan over 256 chunks
        for (int off = 1; off < 256; off <<= 1) {
            unsigned v = (tid + off < 256) ? csum[tid + off] : 0u;
            __syncthreads();
            csum[tid] += v;
            __syncthreads();
        }
        {   // locate chunk holding the 256th (valid chunks are >=128)
            unsigned above = (tid < 255) ? csum[tid + 1] : 0u;
            if (tid >= 128 && csum[tid] >= KTOP && above < KTOP) {
                sel_c = (unsigned)tid; sel_a = above;
            }
        }
        __syncthreads();
        if (tid == 0) {
            if (sel_c == 0xFFFFFFFFu) {
                tsh = 2048u << 20;          // fewer than k valid: take all
            } else {
                unsigned cum = sel_a, bin = 2048;
                for (int bb = (int)sel_c * 16 + 15; bb >= (int)sel_c * 16; --bb) {
                    unsigned hb = lh[bb];
                    if (cum + hb >= KTOP) { bin = (unsigned)bb; break; }
                    cum += hb;
                }
                tsh = bin << 20;
            }
        }
        __syncthreads();
        // pass 2: emit; exact-T ties gated to <= KTOP
        unsigned T = tsh;
        unsigned base = (unsigned)gblk * CAP;
#pragma unroll
        for (int ni = 0; ni < 4; ni++) {
            int jl = n0 + ni * 16 + lane15;
            int v2 = (unsigned)jl < nv2v;
#pragma unroll
            for (int r = 0; r < 4; r++) {
                int il = m0 + wave * 16 + quad * 4 + r;
                float s = acc[ni][r] + bias;
                s = s > 0.f ? s : 0.f;
                unsigned key = (v2 && (unsigned)il < nv1v)
                                   ? (__float_as_uint(s) | 0x80000000u) : 0u;
                if (key > T) {
                    unsigned p = atomicAdd(&lcnt, 1u);
                    if (p < CAP) cand[base + p] = key;
                } else if (key == T) {
                    unsigned z = atomicAdd(&zeq, 1u);
                    if (z < KTOP) {
                        unsigned p = atomicAdd(&lcnt, 1u);
                        if (p < CAP) cand[base + p] = key;
                    }
                }
            }
        }
        __syncthreads();
        if (tid == 0) cnt[gblk] = lcnt < CAP ? lcnt : CAP;
        __syncthreads();
    }
}

// ---- final: per batch, EXACT top-256 via 3-pass LDS radix select ----
__global__ __launch_bounds__(1024) void final_kernel(
    const unsigned* __restrict__ cand, const unsigned* __restrict__ cnt,
    float* __restrict__ out) {
    __shared__ unsigned buf[FBUF];     // 64 KB
    __shared__ unsigned h[NBIN];       // 16 KB
    __shared__ unsigned ss[256];
    __shared__ unsigned scnt_s[NT], off_s[NT];
    __shared__ unsigned ntot_s, sel_c, sel_a, B_s, R_s, mcount;
    __shared__ int have_s;
    __shared__ unsigned srt[256];
    int b = blockIdx.x, tid = threadIdx.x;
    int wv = tid >> 6, ln = tid & 63;

    if (tid < NT) {
        unsigned c = cnt[b * NT + tid];
        scnt_s[tid] = c < CAP ? c : CAP;
    }
    __syncthreads();
    if (tid == 0) {
        unsigned o = 0;
        for (int i = 0; i < NT; i++) {
            unsigned c = scnt_s[i];
            if (o + c > FBUF) c = (o < FBUF) ? FBUF - o : 0;
            scnt_s[i] = c;
            off_s[i] = o;
            o += c;
        }
        ntot_s = o;
        have_s = 1;
    }
    __syncthreads();
    // wave-parallel staging: wave wv handles segments wv, wv+16, ...
    for (int s = wv; s < NT; s += 16) {
        unsigned c = scnt_s[s], o = off_s[s];
        const unsigned* p = cand + (size_t)(b * NT + s) * CAP;
        for (unsigned i = ln; i < c; i += 64) buf[o + i] = p[i];
    }
    __syncthreads();
    unsigned n = ntot_s;

    unsigned Kr = KTOP;
    unsigned pfx = 0;
    unsigned kth = 0;
    for (int pass = 0; pass < 3; pass++) {
        int bins = (pass < 2) ? NBIN : 256;
        int shift = (pass == 0) ? 20 : (pass == 1) ? 8 : 0;
        int nch = bins >> 4;
        for (int i = tid; i < bins; i += 1024) h[i] = 0;
        __syncthreads();
        for (unsigned i = tid; i < n; i += 1024) {
            unsigned k = buf[i];
            bool ok = (pass == 0) ||
                      (pass == 1 && (k >> 20) == pfx) ||
                      (pass == 2 && (k >> 8) == pfx);
            if (ok) atomicAdd(&h[(k >> shift) & (bins - 1)], 1u);
        }
        __syncthreads();
        if (tid < nch) {
            unsigned s = 0;
#pragma unroll
            for (int i = 0; i < 16; i++) s += h[tid * 16 + i];
            ss[tid] = s;
        }
        __syncthreads();
        for (int off = 1; off < nch; off <<= 1) {
            unsigned v = 0;
            if (tid < nch && tid + (unsigned)off < (unsigned)nch) v = ss[tid + off];
            __syncthreads();
            if (tid < nch) ss[tid] += v;
            __syncthreads();
        }
        if (pass == 0) {
            if (tid == 0) have_s = (ss[0] >= KTOP);
            __syncthreads();
            if (!have_s) break;
        }
        if (tid < nch) {
            unsigned above = (tid + 1 < (unsigned)nch) ? ss[tid + 1] : 0u;
            if (above < Kr && ss[tid] >= Kr) { sel_c = tid; sel_a = above; }
        }
        __syncthreads();
        if (tid == 0) {
            unsigned cum = sel_a;
            for (int bb = (int)sel_c * 16 + 15; bb >= (int)sel_c * 16; --bb) {
                unsigned hb = h[bb];
                if (cum + hb >= Kr) { B_s = (unsigned)bb; R_s = Kr - cum; break; }
                cum += hb;
            }
        }
        __syncthreads();
        unsigned Bv = B_s;
        Kr = R_s;
        if (pass == 0) pfx = Bv;
        else if (pass == 1) pfx = (pfx << 12) | Bv;
        else kth = (pfx << 8) | Bv;
        __syncthreads();
    }

    if (tid == 0) mcount = 0;
    __syncthreads();
    int have = have_s;
    unsigned lim = have ? kth : 0u;
    for (unsigned i = tid; i < n; i += 1024) {
        unsigned k = buf[i];
        if (k > lim) {
            unsigned p = atomicAdd(&mcount, 1u);
            if (p < 256) srt[p] = k;
        }
    }
    __syncthreads();
    unsigned m = mcount;
    if (tid < 256 && tid >= (int)m) srt[tid] = have ? kth : 0u;
    for (int k2 = 2; k2 <= 256; k2 <<= 1) {
        for (int j2 = k2 >> 1; j2 > 0; j2 >>= 1) {
            __syncthreads();
            if (tid < 256) {
                int ixj = tid ^ j2;
                if (ixj > tid) {
                    unsigned a = srt[tid], c = srt[ixj];
                    bool up = (tid & k2) == 0;
                    if (up ? (a < c) : (a > c)) { srt[tid] = c; srt[ixj] = a; }
                }
            }
        }
    }
    __syncthreads();
    if (tid < 256) {
        unsigned nval = have ? KTOP : (m < KTOP ? m : KTOP);
        float v;
        if ((unsigned)tid < nval) v = decode_key(srt[tid]);
        else v = (nval > 0) ? decode_key(srt[nval - 1]) : -__builtin_inff();
        out[b * KTOP + tid] = v;
    }
}

// ---------------- launch ----------------
extern "C" void kernel_launch(void* const* d_in, const int* in_sizes, int n_in,
                              void* d_out, int out_size, void* d_ws, size_t ws_size,
                              hipStream_t stream) {
    const float* in1   = (const float*)d_in[0];   // [512,32,1024]
    const float* in2   = (const float*)d_in[1];   // [512,32,1024]
    const int*   mask1 = (const int*)d_in[2];     // [512,32]
    const int*   mask2 = (const int*)d_in[3];     // [512,32]
    const float* W     = (const float*)d_in[4];   // [1024,1024]
    const float* bias  = (const float*)d_in[5];   // [1]
    float* out = (float*)d_out;

    char* ws = (char*)d_ws;
    size_t off = 0;
    const size_t nElem = (size_t)512 * BC * DC;
    unsigned short* A1c = (unsigned short*)(ws + off); off += nElem * 2;      // 32 MB
    unsigned short* A2c = (unsigned short*)(ws + off); off += nElem * 2;      // 32 MB
    unsigned short* Wb  = (unsigned short*)(ws + off); off += (size_t)DC * DC * 2; // 2 MB
    unsigned short* V   = (unsigned short*)(ws + off); off += nElem * 2;      // 32 MB
    unsigned* cand = (unsigned*)(ws + off); off += (size_t)BC * NT * CAP * 4; // 4 MB
    unsigned* cnt  = (unsigned*)(ws + off); off += (size_t)BC * NT * 4;
    int* idx1 = (int*)(ws + off); off += (size_t)BC * 512 * 4;
    int* idx2 = (int*)(ws + off); off += (size_t)BC * 512 * 4;
    unsigned* nv1 = (unsigned*)(ws + off); off += BC * 4;
    unsigned* nv2 = (unsigned*)(ws + off); off += BC * 4;
    unsigned* wl  = (unsigned*)(ws + off); off += 2048 * 4;
    unsigned* wcount = (unsigned*)(ws + off); off += 4;

    scan_kernel<<<BC, 512, 0, stream>>>(mask1, mask2, idx1, idx2, nv1, nv2, cnt);
    wl_kernel<<<1, 256, 0, stream>>>(nv1, nv2, wl, wcount);
    prep_kernel<<<2 * 16384 + 1024, 256, 0, stream>>>(
        in1, in2, W, idx1, idx2, nv1, nv2, A1c, A2c, Wb);
    gemm1_kernel<<<dim3(128, 8), 512, 0, stream>>>(A2c, Wb, V, nv2);
    gemm2_kernel<<<768, 256, 0, stream>>>(A1c, V, nv1, nv2, bias, cand, cnt,
                                          wl, wcount);
    final_kernel<<<BC, 1024, 0, stream>>>(cand, cnt, out);
}

// Round 9
// 243.305 us; speedup vs baseline: 1.0346x; 1.0029x over previous
//
#include <hip/hip_runtime.h>

typedef __bf16 bf16_t;
typedef bf16_t bf16x8 __attribute__((ext_vector_type(8)));
typedef float floatx4 __attribute__((ext_vector_type(4)));

#define L1C 512
#define L2C 512
#define BC  32
#define DC  1024
#define KTOP 256
#define NBIN 4096           // 12-bit bins: sign+exp+3 mantissa bits
#define CAP  512            // per-tile candidate slots (64x64 tile)
#define NT   64             // tiles per batch in gemm2 (8x8)
#define FBUF 16384          // final-stage LDS candidate buffer

__device__ __forceinline__ unsigned short f2bf(float f) {
    unsigned u = __float_as_uint(f);
    u += 0x7FFFu + ((u >> 16) & 1u);   // RNE (data has no NaNs)
    return (unsigned short)(u >> 16);
}

// async global->LDS, 16B per lane; LDS dest = wave-uniform base + lane*16
__device__ __forceinline__ void g2l16(const unsigned short* g, unsigned short* l) {
    __builtin_amdgcn_global_load_lds((const unsigned int*)g, (unsigned int*)l,
                                     16, 0, 0);
}

__device__ __forceinline__ float decode_key(unsigned k) {
    return __uint_as_float(k & 0x7FFFFFFFu);
}

#define CFENCE asm volatile("" ::: "memory")

// ---- scan: per-batch valid-row index lists for both masks + cnt zero ----
__global__ __launch_bounds__(512) void scan_kernel(
    const int* __restrict__ mask1, const int* __restrict__ mask2,
    int* __restrict__ idx1, int* __restrict__ idx2,
    unsigned* __restrict__ nv1, unsigned* __restrict__ nv2,
    unsigned* __restrict__ cnt) {
    __shared__ unsigned sc[512];
    int b = blockIdx.x, t = threadIdx.x;
    for (int which = 0; which < 2; which++) {
        const int* m = which ? mask2 : mask1;
        int* idx = which ? idx2 : idx1;
        unsigned v = (m[t * BC + b] == 0) ? 1u : 0u;
        sc[t] = v;
        __syncthreads();
        for (int off = 1; off < 512; off <<= 1) {
            unsigned x = (t >= off) ? sc[t - off] : 0u;
            __syncthreads();
            sc[t] += x;
            __syncthreads();
        }
        if (v) idx[b * 512 + sc[t] - 1] = t;
        if (t == 511) { if (which) nv2[b] = sc[511]; else nv1[b] = sc[511]; }
        __syncthreads();
    }
    if (t < NT) cnt[b * NT + t] = 0;
}

// ---- wl: deterministic gemm2 tile worklist (single block, no atomics) ----
__global__ __launch_bounds__(256) void wl_kernel(
    const unsigned* __restrict__ nv1, const unsigned* __restrict__ nv2,
    unsigned* __restrict__ wl, unsigned* __restrict__ wcount) {
    __shared__ unsigned t1s[BC], t2s[BC], offs[BC + 1];
    int tid = threadIdx.x;
    if (tid < BC) {
        unsigned p1 = (nv1[tid] + 63u) & ~63u, p2 = (nv2[tid] + 63u) & ~63u;
        t1s[tid] = p1 >> 6; t2s[tid] = p2 >> 6;   // tiles per dim (<=8)
    }
    __syncthreads();
    if (tid == 0) {
        unsigned o = 0;
        for (int b = 0; b < BC; b++) { offs[b] = o; o += t1s[b] * t2s[b]; }
        offs[BC] = o;
        *wcount = o;
    }
    __syncthreads();
    for (int b = 0; b < BC; b++) {
        unsigned nt = t1s[b] * t2s[b], o = offs[b], t2 = t2s[b];
        for (unsigned i = tid; i < nt; i += 256)
            wl[o + i] = ((unsigned)b << 6) | ((i / t2) << 3) | (i % t2);
    }
}

// ---- prep: compacting casts of in1/in2 (+zero pad to x64), W cast ----
__global__ __launch_bounds__(256) void prep_kernel(
    const float* __restrict__ in1, const float* __restrict__ in2,
    const float* __restrict__ W,
    const int* __restrict__ idx1, const int* __restrict__ idx2,
    const unsigned* __restrict__ nv1, const unsigned* __restrict__ nv2,
    unsigned short* __restrict__ A1c, unsigned short* __restrict__ A2c,
    unsigned short* __restrict__ Wb) {
    int r = blockIdx.x, t = threadIdx.x;
    const float* src;
    unsigned short* dst;
    if (r < 2 * 16384) {
        int which = r >> 14;            // 0: in1, 1: in2
        int rr = r & 16383;
        int b = rr >> 9, vi = rr & 511;
        unsigned nv = which ? nv2[b] : nv1[b];
        unsigned pad = (nv + 63u) & ~63u;
        if ((unsigned)vi >= pad) return;
        dst = (which ? A2c : A1c) + ((size_t)b * 512 + vi) * DC;
        if ((unsigned)vi < nv) {
            int l = (which ? idx2 : idx1)[b * 512 + vi];
            src = (which ? in2 : in1) + (size_t)(l * BC + b) * DC;
        } else {
            ushort4 z = {0, 0, 0, 0};
            reinterpret_cast<ushort4*>(dst)[t] = z;
            return;
        }
    } else {
        int r3 = r - 2 * 16384;
        src = W + (size_t)r3 * DC;
        dst = Wb + (size_t)r3 * DC;
    }
    float4 v = reinterpret_cast<const float4*>(src)[t];
    ushort4 o;
    o.x = f2bf(v.x); o.y = f2bf(v.y); o.z = f2bf(v.z); o.w = f2bf(v.w);
    reinterpret_cast<ushort4*>(dst)[t] = o;
}

// ---- GEMM1: V[b][j][d] = sum_e A2c[b][j][e] * Wb[d][e] ----
// 128x128 tile, BK=64, 256 threads (4 waves 2x2), counted-vmcnt double
// buffer (round-3 proven config, 42.9us).
__global__ __launch_bounds__(256) void gemm1_kernel(
    const unsigned short* __restrict__ A,    // A2c [32][512][1024]
    const unsigned short* __restrict__ Bt,   // Wb  [1024][1024]
    unsigned short* __restrict__ C,          // V   [32][512][1024]
    const unsigned* __restrict__ nv2) {
    int bi = blockIdx.x >> 2, mt = blockIdx.x & 3;
    unsigned pad2 = (nv2[bi] + 63u) & ~63u;
    if ((unsigned)(mt * 128) >= pad2) return;
    __shared__ unsigned short As0[2][128][32];   // [khalf][row][col]
    __shared__ unsigned short Bs0[2][128][32];
    __shared__ unsigned short As1[2][128][32];
    __shared__ unsigned short Bs1[2][128][32];
    int tid = threadIdx.x;
    int wave = tid >> 6, lane = tid & 63;
    int lane15 = lane & 15, quad = lane >> 4;
    int wm = wave >> 1, wn = wave & 1;
    size_t m0 = (size_t)bi * 512 + mt * 128;
    size_t n0 = (size_t)blockIdx.y * 128;

    floatx4 zero = {0.f, 0.f, 0.f, 0.f};
    floatx4 acc[4][4];
#pragma unroll
    for (int i = 0; i < 4; i++)
#pragma unroll
        for (int j = 0; j < 4; j++) acc[i][j] = zero;

    auto stage = [&](unsigned short* la, unsigned short* lb, int k0) {
        // A: 1024 16B-units (4 chunks); unit idx = h*512 + row*4 + u
#pragma unroll
        for (int c = 0; c < 4; c++) {
            int cid = c * 256 + tid;
            int h = cid >> 9, row = (cid >> 2) & 127, col8 = (cid & 3) * 8;
            g2l16(&A[(m0 + row) * DC + k0 + h * 32 + col8],
                  la + (c * 256 + wave * 64) * 8);
        }
#pragma unroll
        for (int c = 0; c < 4; c++) {
            int cid = c * 256 + tid;
            int h = cid >> 9, row = (cid >> 2) & 127, col8 = (cid & 3) * 8;
            g2l16(&Bt[(n0 + row) * DC + k0 + h * 32 + col8],
                  lb + (c * 256 + wave * 64) * 8);
        }
    };

    stage(&As0[0][0][0], &Bs0[0][0][0], 0);
#pragma unroll
    for (int t = 0; t < DC / 64; t++) {
        const unsigned short* curA = (t & 1) ? &As1[0][0][0] : &As0[0][0][0];
        const unsigned short* curB = (t & 1) ? &Bs1[0][0][0] : &Bs0[0][0][0];
        if (t + 1 < DC / 64) {
            unsigned short* nxtA = (t & 1) ? &As0[0][0][0] : &As1[0][0][0];
            unsigned short* nxtB = (t & 1) ? &Bs0[0][0][0] : &Bs1[0][0][0];
            stage(nxtA, nxtB, (t + 1) * 64);
            asm volatile("s_waitcnt vmcnt(8)" ::: "memory");  // tile t landed
        } else {
            asm volatile("s_waitcnt vmcnt(0)" ::: "memory");
        }
        __builtin_amdgcn_s_barrier();
        CFENCE;
#pragma unroll
        for (int h = 0; h < 2; h++) {
            bf16x8 af[4], bfr[4];
#pragma unroll
            for (int mi = 0; mi < 4; mi++)
                af[mi] = *reinterpret_cast<const bf16x8*>(
                    curA + h * 4096 + (wm * 64 + mi * 16 + lane15) * 32 + quad * 8);
#pragma unroll
            for (int ni = 0; ni < 4; ni++)
                bfr[ni] = *reinterpret_cast<const bf16x8*>(
                    curB + h * 4096 + (wn * 64 + ni * 16 + lane15) * 32 + quad * 8);
#pragma unroll
            for (int mi = 0; mi < 4; mi++)
#pragma unroll
                for (int ni = 0; ni < 4; ni++)
                    acc[mi][ni] = __builtin_amdgcn_mfma_f32_16x16x32_bf16(
                        af[mi], bfr[ni], acc[mi][ni], 0, 0, 0);
        }
        if (t + 1 < DC / 64) {
            CFENCE;
            __builtin_amdgcn_s_barrier();   // reads of cur done before overwrite
            CFENCE;
        }
    }
#pragma unroll
    for (int mi = 0; mi < 4; mi++)
#pragma unroll
        for (int ni = 0; ni < 4; ni++)
#pragma unroll
            for (int r = 0; r < 4; r++) {
                size_t row = m0 + wm * 64 + mi * 16 + quad * 4 + r;
                size_t col = n0 + wn * 64 + ni * 16 + lane15;
                C[row * DC + col] = f2bf(acc[mi][ni][r]);
            }
}

// ---- GEMM2: persistent blocks over device-built 64x64 tile worklist;
//      counted-vmcnt double buffer; relu + bias; top-k candidates ----
__global__ __launch_bounds__(256) void gemm2_kernel(
    const unsigned short* __restrict__ A1c,  // [32][512][1024]
    const unsigned short* __restrict__ V,    // [32][512][1024]
    const unsigned* __restrict__ nv1, const unsigned* __restrict__ nv2,
    const float* __restrict__ bptr,
    unsigned* __restrict__ cand,             // [32*NT][CAP]
    unsigned* __restrict__ cnt,              // [32*NT]
    const unsigned* __restrict__ wl, const unsigned* __restrict__ wcount) {
    __shared__ unsigned short As0[2][64][32];   // [khalf][row][col]
    __shared__ unsigned short Bs0[2][64][32];
    __shared__ unsigned short As1[2][64][32];
    __shared__ unsigned short Bs1[2][64][32];
    __shared__ unsigned lh[NBIN];
    __shared__ unsigned csum[256];
    __shared__ unsigned sel_c, sel_a, tsh, lcnt, zeq;
    int tid = threadIdx.x;
    int wave = tid >> 6, lane = tid & 63;
    int lane15 = lane & 15, quad = lane >> 4;
    unsigned nwork = *wcount;
    float bias = bptr[0];
    // XCD-chunked order: consecutive worklist entries (same batch) stay on
    // the same XCD for L2 reuse of the batch's A/V panels.
    unsigned chunk = gridDim.x >> 3;
    unsigned w0 = (blockIdx.x & 7) * chunk + (blockIdx.x >> 3);

    for (unsigned w = w0; w < nwork; w += gridDim.x) {
        unsigned d = wl[w];
        int b = d >> 6, ty = (d >> 3) & 7, tx = d & 7;
        int m0 = ty * 64, n0 = tx * 64;
        int gblk = b * NT + ty * 8 + tx;
        unsigned nv1v = nv1[b], nv2v = nv2[b];
        const unsigned short* Ab = A1c + (size_t)b * 512 * DC;
        const unsigned short* Bb = V + (size_t)b * 512 * DC;

        for (int i = tid; i < NBIN; i += 256) lh[i] = 0;
        if (tid == 0) { sel_c = 0xFFFFFFFFu; lcnt = 0; zeq = 0; }

        floatx4 zero = {0.f, 0.f, 0.f, 0.f};
        floatx4 acc[4];
#pragma unroll
        for (int i = 0; i < 4; i++) acc[i] = zero;

        auto stage = [&](unsigned short* la, unsigned short* lb, int k0) {
#pragma unroll
            for (int c = 0; c < 2; c++) {
                int cid = c * 256 + tid;   // [0,512)
                int h = cid >> 8, row = (cid >> 2) & 63, col8 = (cid & 3) * 8;
                g2l16(&Ab[(size_t)(m0 + row) * DC + k0 + h * 32 + col8],
                      la + (c * 256 + wave * 64) * 8);
                g2l16(&Bb[(size_t)(n0 + row) * DC + k0 + h * 32 + col8],
                      lb + (c * 256 + wave * 64) * 8);
            }
        };

        stage(&As0[0][0][0], &Bs0[0][0][0], 0);
#pragma unroll
        for (int t = 0; t < DC / 64; t++) {
            const unsigned short* curA = (t & 1) ? &As1[0][0][0] : &As0[0][0][0];
            const unsigned short* curB = (t & 1) ? &Bs1[0][0][0] : &Bs0[0][0][0];
            if (t + 1 < DC / 64) {
                unsigned short* nxtA = (t & 1) ? &As0[0][0][0] : &As1[0][0][0];
                unsigned short* nxtB = (t & 1) ? &Bs0[0][0][0] : &Bs1[0][0][0];
                stage(nxtA, nxtB, (t + 1) * 64);
                asm volatile("s_waitcnt vmcnt(4)" ::: "memory");  // tile t landed
            } else {
                asm volatile("s_waitcnt vmcnt(0)" ::: "memory");
            }
            __builtin_amdgcn_s_barrier();
            CFENCE;
#pragma unroll
            for (int h = 0; h < 2; h++) {
                bf16x8 af, bfr[4];
                af = *reinterpret_cast<const bf16x8*>(
                    curA + h * 2048 + (wave * 16 + lane15) * 32 + quad * 8);
#pragma unroll
                for (int ni = 0; ni < 4; ni++)
                    bfr[ni] = *reinterpret_cast<const bf16x8*>(
                        curB + h * 2048 + (ni * 16 + lane15) * 32 + quad * 8);
#pragma unroll
                for (int ni = 0; ni < 4; ni++)
                    acc[ni] = __builtin_amdgcn_mfma_f32_16x16x32_bf16(
                        af, bfr[ni], acc[ni], 0, 0, 0);
            }
            CFENCE;
            __builtin_amdgcn_s_barrier();
            CFENCE;
        }

        // pass 1: 4096-bin histogram (zero scores privatized)
        unsigned zc = 0;
#pragma unroll
        for (int ni = 0; ni < 4; ni++) {
            int jl = n0 + ni * 16 + lane15;
            int v2 = (unsigned)jl < nv2v;
#pragma unroll
            for (int r = 0; r < 4; r++) {
                int il = m0 + wave * 16 + quad * 4 + r;
                float s = acc[ni][r] + bias;
                if (v2 && (unsigned)il < nv1v) {
                    if (s > 0.f)
                        atomicAdd(&lh[(__float_as_uint(s) | 0x80000000u) >> 20], 1u);
                    else
                        zc++;
                }
            }
        }
        if (zc) atomicAdd(&lh[2048], zc);
        __syncthreads();
        unsigned s16 = 0;
#pragma unroll
        for (int i = 0; i < 16; i++) s16 += lh[tid * 16 + i];
        csum[tid] = s16;
        __syncthreads();
        // parallel suffix scan over 256 chunks
        for (int off = 1; off < 256; off <<= 1) {
            unsigned v = (tid + off < 256) ? csum[tid + off] : 0u;
            __syncthreads();
            csum[tid] += v;
            __syncthreads();
        }
        {   // locate chunk holding the 256th (valid chunks are >=128)
            unsigned above = (tid < 255) ? csum[tid + 1] : 0u;
            if (tid >= 128 && csum[tid] >= KTOP && above < KTOP) {
                sel_c = (unsigned)tid; sel_a = above;
            }
        }
        __syncthreads();
        if (tid == 0) {
            if (sel_c == 0xFFFFFFFFu) {
                tsh = 2048u << 20;          // fewer than k valid: take all
            } else {
                unsigned cum = sel_a, bin = 2048;
                for (int bb = (int)sel_c * 16 + 15; bb >= (int)sel_c * 16; --bb) {
                    unsigned hb = lh[bb];
                    if (cum + hb >= KTOP) { bin = (unsigned)bb; break; }
                    cum += hb;
                }
                tsh = bin << 20;
            }
        }
        __syncthreads();
        // pass 2: emit; exact-T ties gated to <= KTOP
        unsigned T = tsh;
        unsigned base = (unsigned)gblk * CAP;
#pragma unroll
        for (int ni = 0; ni < 4; ni++) {
            int jl = n0 + ni * 16 + lane15;
            int v2 = (unsigned)jl < nv2v;
#pragma unroll
            for (int r = 0; r < 4; r++) {
                int il = m0 + wave * 16 + quad * 4 + r;
                float s = acc[ni][r] + bias;
                s = s > 0.f ? s : 0.f;
                unsigned key = (v2 && (unsigned)il < nv1v)
                                   ? (__float_as_uint(s) | 0x80000000u) : 0u;
                if (key > T) {
                    unsigned p = atomicAdd(&lcnt, 1u);
                    if (p < CAP) cand[base + p] = key;
                } else if (key == T) {
                    unsigned z = atomicAdd(&zeq, 1u);
                    if (z < KTOP) {
                        unsigned p = atomicAdd(&lcnt, 1u);
                        if (p < CAP) cand[base + p] = key;
                    }
                }
            }
        }
        __syncthreads();
        if (tid == 0) cnt[gblk] = lcnt < CAP ? lcnt : CAP;
        __syncthreads();
    }
}

// ---- final: per batch, EXACT top-256 via 3-pass LDS radix select ----
__global__ __launch_bounds__(1024) void final_kernel(
    const unsigned* __restrict__ cand, const unsigned* __restrict__ cnt,
    float* __restrict__ out) {
    __shared__ unsigned buf[FBUF];     // 64 KB
    __shared__ unsigned h[NBIN];       // 16 KB
    __shared__ unsigned ss[256];
    __shared__ unsigned scnt_s[NT], off_s[NT];
    __shared__ unsigned ntot_s, sel_c, sel_a, B_s, R_s, mcount;
    __shared__ int have_s;
    __shared__ unsigned srt[256];
    int b = blockIdx.x, tid = threadIdx.x;
    int wv = tid >> 6, ln = tid & 63;

    if (tid < NT) {
        unsigned c = cnt[b * NT + tid];
        scnt_s[tid] = c < CAP ? c : CAP;
    }
    __syncthreads();
    if (tid == 0) {
        unsigned o = 0;
        for (int i = 0; i < NT; i++) {
            unsigned c = scnt_s[i];
            if (o + c > FBUF) c = (o < FBUF) ? FBUF - o : 0;
            scnt_s[i] = c;
            off_s[i] = o;
            o += c;
        }
        ntot_s = o;
        have_s = 1;
    }
    __syncthreads();
    // wave-parallel staging: wave wv handles segments wv, wv+16, ...
    for (int s = wv; s < NT; s += 16) {
        unsigned c = scnt_s[s], o = off_s[s];
        const unsigned* p = cand + (size_t)(b * NT + s) * CAP;
        for (unsigned i = ln; i < c; i += 64) buf[o + i] = p[i];
    }
    __syncthreads();
    unsigned n = ntot_s;

    unsigned Kr = KTOP;
    unsigned pfx = 0;
    unsigned kth = 0;
    for (int pass = 0; pass < 3; pass++) {
        int bins = (pass < 2) ? NBIN : 256;
        int shift = (pass == 0) ? 20 : (pass == 1) ? 8 : 0;
        int nch = bins >> 4;
        for (int i = tid; i < bins; i += 1024) h[i] = 0;
        __syncthreads();
        for (unsigned i = tid; i < n; i += 1024) {
            unsigned k = buf[i];
            bool ok = (pass == 0) ||
                      (pass == 1 && (k >> 20) == pfx) ||
                      (pass == 2 && (k >> 8) == pfx);
            if (ok) atomicAdd(&h[(k >> shift) & (bins - 1)], 1u);
        }
        __syncthreads();
        if (tid < nch) {
            unsigned s = 0;
#pragma unroll
            for (int i = 0; i < 16; i++) s += h[tid * 16 + i];
            ss[tid] = s;
        }
        __syncthreads();
        for (int off = 1; off < nch; off <<= 1) {
            unsigned v = 0;
            if (tid < nch && tid + (unsigned)off < (unsigned)nch) v = ss[tid + off];
            __syncthreads();
            if (tid < nch) ss[tid] += v;
            __syncthreads();
        }
        if (pass == 0) {
            if (tid == 0) have_s = (ss[0] >= KTOP);
            __syncthreads();
            if (!have_s) break;
        }
        if (tid < nch) {
            unsigned above = (tid + 1 < (unsigned)nch) ? ss[tid + 1] : 0u;
            if (above < Kr && ss[tid] >= Kr) { sel_c = tid; sel_a = above; }
        }
        __syncthreads();
        if (tid == 0) {
            unsigned cum = sel_a;
            for (int bb = (int)sel_c * 16 + 15; bb >= (int)sel_c * 16; --bb) {
                unsigned hb = h[bb];
                if (cum + hb >= Kr) { B_s = (unsigned)bb; R_s = Kr - cum; break; }
                cum += hb;
            }
        }
        __syncthreads();
        unsigned Bv = B_s;
        Kr = R_s;
        if (pass == 0) pfx = Bv;
        else if (pass == 1) pfx = (pfx << 12) | Bv;
        else kth = (pfx << 8) | Bv;
        __syncthreads();
    }

    if (tid == 0) mcount = 0;
    __syncthreads();
    int have = have_s;
    unsigned lim = have ? kth : 0u;
    for (unsigned i = tid; i < n; i += 1024) {
        unsigned k = buf[i];
        if (k > lim) {
            unsigned p = atomicAdd(&mcount, 1u);
            if (p < 256) srt[p] = k;
        }
    }
    __syncthreads();
    unsigned m = mcount;
    if (tid < 256 && tid >= (int)m) srt[tid] = have ? kth : 0u;
    for (int k2 = 2; k2 <= 256; k2 <<= 1) {
        for (int j2 = k2 >> 1; j2 > 0; j2 >>= 1) {
            __syncthreads();
            if (tid < 256) {
                int ixj = tid ^ j2;
                if (ixj > tid) {
                    unsigned a = srt[tid], c = srt[ixj];
                    bool up = (tid & k2) == 0;
                    if (up ? (a < c) : (a > c)) { srt[tid] = c; srt[ixj] = a; }
                }
            }
        }
    }
    __syncthreads();
    if (tid < 256) {
        unsigned nval = have ? KTOP : (m < KTOP ? m : KTOP);
        float v;
        if ((unsigned)tid < nval) v = decode_key(srt[tid]);
        else v = (nval > 0) ? decode_key(srt[nval - 1]) : -__builtin_inff();
        out[b * KTOP + tid] = v;
    }
}

// ---------------- launch ----------------
extern "C" void kernel_launch(void* const* d_in, const int* in_sizes, int n_in,
                              void* d_out, int out_size, void* d_ws, size_t ws_size,
                              hipStream_t stream) {
    const float* in1   = (const float*)d_in[0];   // [512,32,1024]
    const float* in2   = (const float*)d_in[1];   // [512,32,1024]
    const int*   mask1 = (const int*)d_in[2];     // [512,32]
    const int*   mask2 = (const int*)d_in[3];     // [512,32]
    const float* W     = (const float*)d_in[4];   // [1024,1024]
    const float* bias  = (const float*)d_in[5];   // [1]
    float* out = (float*)d_out;

    char* ws = (char*)d_ws;
    size_t off = 0;
    const size_t nElem = (size_t)512 * BC * DC;
    unsigned short* A1c = (unsigned short*)(ws + off); off += nElem * 2;      // 32 MB
    unsigned short* A2c = (unsigned short*)(ws + off); off += nElem * 2;      // 32 MB
    unsigned short* Wb  = (unsigned short*)(ws + off); off += (size_t)DC * DC * 2; // 2 MB
    unsigned short* V   = (unsigned short*)(ws + off); off += nElem * 2;      // 32 MB
    unsigned* cand = (unsigned*)(ws + off); off += (size_t)BC * NT * CAP * 4; // 4 MB
    unsigned* cnt  = (unsigned*)(ws + off); off += (size_t)BC * NT * 4;
    int* idx1 = (int*)(ws + off); off += (size_t)BC * 512 * 4;
    int* idx2 = (int*)(ws + off); off += (size_t)BC * 512 * 4;
    unsigned* nv1 = (unsigned*)(ws + off); off += BC * 4;
    unsigned* nv2 = (unsigned*)(ws + off); off += BC * 4;
    unsigned* wl  = (unsigned*)(ws + off); off += 2048 * 4;
    unsigned* wcount = (unsigned*)(ws + off); off += 4;

    scan_kernel<<<BC, 512, 0, stream>>>(mask1, mask2, idx1, idx2, nv1, nv2, cnt);
    wl_kernel<<<1, 256, 0, stream>>>(nv1, nv2, wl, wcount);
    prep_kernel<<<2 * 16384 + 1024, 256, 0, stream>>>(
        in1, in2, W, idx1, idx2, nv1, nv2, A1c, A2c, Wb);
    gemm1_kernel<<<dim3(128, 8), 256, 0, stream>>>(A2c, Wb, V, nv2);
    gemm2_kernel<<<768, 256, 0, stream>>>(A1c, V, nv1, nv2, bias, cand, cnt,
                                          wl, wcount);
    final_kernel<<<BC, 1024, 0, stream>>>(cand, cnt, out);
}

// Round 11
// 242.908 us; speedup vs baseline: 1.0362x; 1.0016x over previous
//
#include <hip/hip_runtime.h>

typedef __bf16 bf16_t;
typedef bf16_t bf16x8 __attribute__((ext_vector_type(8)));
typedef float floatx4 __attribute__((ext_vector_type(4)));

#define L1C 512
#define L2C 512
#define BC  32
#define DC  1024
#define KTOP 256
#define NBIN 4096           // 12-bit bins: sign+exp+3 mantissa bits
#define CAP  512            // per-tile candidate slots (64x64 tile)
#define NT   64             // tiles per batch in gemm2 (8x8)
#define FBUF 16384          // final-stage LDS candidate buffer

__device__ __forceinline__ unsigned short f2bf(float f) {
    unsigned u = __float_as_uint(f);
    u += 0x7FFFu + ((u >> 16) & 1u);   // RNE (data has no NaNs)
    return (unsigned short)(u >> 16);
}

// async global->LDS, 16B per lane; LDS dest = wave-uniform base + lane*16
__device__ __forceinline__ void g2l16(const unsigned short* g, unsigned short* l) {
    __builtin_amdgcn_global_load_lds((const unsigned int*)g, (unsigned int*)l,
                                     16, 0, 0);
}

__device__ __forceinline__ float decode_key(unsigned k) {
    return __uint_as_float(k & 0x7FFFFFFFu);
}

#define CFENCE asm volatile("" ::: "memory")

// ---- scan: per-batch valid-row index lists for both masks + cnt zero ----
__global__ __launch_bounds__(512) void scan_kernel(
    const int* __restrict__ mask1, const int* __restrict__ mask2,
    int* __restrict__ idx1, int* __restrict__ idx2,
    unsigned* __restrict__ nv1, unsigned* __restrict__ nv2,
    unsigned* __restrict__ cnt) {
    __shared__ unsigned sc[512];
    int b = blockIdx.x, t = threadIdx.x;
    for (int which = 0; which < 2; which++) {
        const int* m = which ? mask2 : mask1;
        int* idx = which ? idx2 : idx1;
        unsigned v = (m[t * BC + b] == 0) ? 1u : 0u;
        sc[t] = v;
        __syncthreads();
        for (int off = 1; off < 512; off <<= 1) {
            unsigned x = (t >= off) ? sc[t - off] : 0u;
            __syncthreads();
            sc[t] += x;
            __syncthreads();
        }
        if (v) idx[b * 512 + sc[t] - 1] = t;
        if (t == 511) { if (which) nv2[b] = sc[511]; else nv1[b] = sc[511]; }
        __syncthreads();
    }
    if (t < NT) cnt[b * NT + t] = 0;
}

// ---- wl: deterministic gemm2 tile worklist (single block, no atomics) ----
__global__ __launch_bounds__(256) void wl_kernel(
    const unsigned* __restrict__ nv1, const unsigned* __restrict__ nv2,
    unsigned* __restrict__ wl, unsigned* __restrict__ wcount) {
    __shared__ unsigned t1s[BC], t2s[BC], offs[BC + 1];
    int tid = threadIdx.x;
    if (tid < BC) {
        unsigned p1 = (nv1[tid] + 63u) & ~63u, p2 = (nv2[tid] + 63u) & ~63u;
        t1s[tid] = p1 >> 6; t2s[tid] = p2 >> 6;   // tiles per dim (<=8)
    }
    __syncthreads();
    if (tid == 0) {
        unsigned o = 0;
        for (int b = 0; b < BC; b++) { offs[b] = o; o += t1s[b] * t2s[b]; }
        offs[BC] = o;
        *wcount = o;
    }
    __syncthreads();
    for (int b = 0; b < BC; b++) {
        unsigned nt = t1s[b] * t2s[b], o = offs[b], t2 = t2s[b];
        for (unsigned i = tid; i < nt; i += 256)
            wl[o + i] = ((unsigned)b << 6) | ((i / t2) << 3) | (i % t2);
    }
}

// ---- prep: compacting casts of in1/in2 (+zero pad to x64), W cast ----
__global__ __launch_bounds__(256) void prep_kernel(
    const float* __restrict__ in1, const float* __restrict__ in2,
    const float* __restrict__ W,
    const int* __restrict__ idx1, const int* __restrict__ idx2,
    const unsigned* __restrict__ nv1, const unsigned* __restrict__ nv2,
    unsigned short* __restrict__ A1c, unsigned short* __restrict__ A2c,
    unsigned short* __restrict__ Wb) {
    int r = blockIdx.x, t = threadIdx.x;
    const float* src;
    unsigned short* dst;
    if (r < 2 * 16384) {
        int which = r >> 14;            // 0: in1, 1: in2
        int rr = r & 16383;
        int b = rr >> 9, vi = rr & 511;
        unsigned nv = which ? nv2[b] : nv1[b];
        unsigned pad = (nv + 63u) & ~63u;
        if ((unsigned)vi >= pad) return;
        dst = (which ? A2c : A1c) + ((size_t)b * 512 + vi) * DC;
        if ((unsigned)vi < nv) {
            int l = (which ? idx2 : idx1)[b * 512 + vi];
            src = (which ? in2 : in1) + (size_t)(l * BC + b) * DC;
        } else {
            ushort4 z = {0, 0, 0, 0};
            reinterpret_cast<ushort4*>(dst)[t] = z;
            return;
        }
    } else {
        int r3 = r - 2 * 16384;
        src = W + (size_t)r3 * DC;
        dst = Wb + (size_t)r3 * DC;
    }
    float4 v = reinterpret_cast<const float4*>(src)[t];
    ushort4 o;
    o.x = f2bf(v.x); o.y = f2bf(v.y); o.z = f2bf(v.z); o.w = f2bf(v.w);
    reinterpret_cast<ushort4*>(dst)[t] = o;
}

// ---- GEMM1: V[b][j][d] = sum_e A2c[b][j][e] * Wb[d][e] ----
// 128x128 tile, BK=64, 256 threads (4 waves 2x2), counted-vmcnt double
// buffer (round-3 proven config, 42.9us).
__global__ __launch_bounds__(256) void gemm1_kernel(
    const unsigned short* __restrict__ A,    // A2c [32][512][1024]
    const unsigned short* __restrict__ Bt,   // Wb  [1024][1024]
    unsigned short* __restrict__ C,          // V   [32][512][1024]
    const unsigned* __restrict__ nv2) {
    int bi = blockIdx.x >> 2, mt = blockIdx.x & 3;
    unsigned pad2 = (nv2[bi] + 63u) & ~63u;
    if ((unsigned)(mt * 128) >= pad2) return;
    __shared__ unsigned short As0[2][128][32];   // [khalf][row][col]
    __shared__ unsigned short Bs0[2][128][32];
    __shared__ unsigned short As1[2][128][32];
    __shared__ unsigned short Bs1[2][128][32];
    int tid = threadIdx.x;
    int wave = tid >> 6, lane = tid & 63;
    int lane15 = lane & 15, quad = lane >> 4;
    int wm = wave >> 1, wn = wave & 1;
    size_t m0 = (size_t)bi * 512 + mt * 128;
    size_t n0 = (size_t)blockIdx.y * 128;

    floatx4 zero = {0.f, 0.f, 0.f, 0.f};
    floatx4 acc[4][4];
#pragma unroll
    for (int i = 0; i < 4; i++)
#pragma unroll
        for (int j = 0; j < 4; j++) acc[i][j] = zero;

    auto stage = [&](unsigned short* la, unsigned short* lb, int k0) {
        // A: 1024 16B-units (4 chunks); unit idx = h*512 + row*4 + u
#pragma unroll
        for (int c = 0; c < 4; c++) {
            int cid = c * 256 + tid;
            int h = cid >> 9, row = (cid >> 2) & 127, col8 = (cid & 3) * 8;
            g2l16(&A[(m0 + row) * DC + k0 + h * 32 + col8],
                  la + (c * 256 + wave * 64) * 8);
        }
#pragma unroll
        for (int c = 0; c < 4; c++) {
            int cid = c * 256 + tid;
            int h = cid >> 9, row = (cid >> 2) & 127, col8 = (cid & 3) * 8;
            g2l16(&Bt[(n0 + row) * DC + k0 + h * 32 + col8],
                  lb + (c * 256 + wave * 64) * 8);
        }
    };

    stage(&As0[0][0][0], &Bs0[0][0][0], 0);
#pragma unroll
    for (int t = 0; t < DC / 64; t++) {
        const unsigned short* curA = (t & 1) ? &As1[0][0][0] : &As0[0][0][0];
        const unsigned short* curB = (t & 1) ? &Bs1[0][0][0] : &Bs0[0][0][0];
        if (t + 1 < DC / 64) {
            unsigned short* nxtA = (t & 1) ? &As0[0][0][0] : &As1[0][0][0];
            unsigned short* nxtB = (t & 1) ? &Bs0[0][0][0] : &Bs1[0][0][0];
            stage(nxtA, nxtB, (t + 1) * 64);
            asm volatile("s_waitcnt vmcnt(8)" ::: "memory");  // tile t landed
        } else {
            asm volatile("s_waitcnt vmcnt(0)" ::: "memory");
        }
        __builtin_amdgcn_s_barrier();
        CFENCE;
#pragma unroll
        for (int h = 0; h < 2; h++) {
            bf16x8 af[4], bfr[4];
#pragma unroll
            for (int mi = 0; mi < 4; mi++)
                af[mi] = *reinterpret_cast<const bf16x8*>(
                    curA + h * 4096 + (wm * 64 + mi * 16 + lane15) * 32 + quad * 8);
#pragma unroll
            for (int ni = 0; ni < 4; ni++)
                bfr[ni] = *reinterpret_cast<const bf16x8*>(
                    curB + h * 4096 + (wn * 64 + ni * 16 + lane15) * 32 + quad * 8);
#pragma unroll
            for (int mi = 0; mi < 4; mi++)
#pragma unroll
                for (int ni = 0; ni < 4; ni++)
                    acc[mi][ni] = __builtin_amdgcn_mfma_f32_16x16x32_bf16(
                        af[mi], bfr[ni], acc[mi][ni], 0, 0, 0);
        }
        if (t + 1 < DC / 64) {
            CFENCE;
            __builtin_amdgcn_s_barrier();   // reads of cur done before overwrite
            CFENCE;
        }
    }
#pragma unroll
    for (int mi = 0; mi < 4; mi++)
#pragma unroll
        for (int ni = 0; ni < 4; ni++)
#pragma unroll
            for (int r = 0; r < 4; r++) {
                size_t row = m0 + wm * 64 + mi * 16 + quad * 4 + r;
                size_t col = n0 + wn * 64 + ni * 16 + lane15;
                C[row * DC + col] = f2bf(acc[mi][ni][r]);
            }
}

// ---- GEMM2: persistent blocks over device-built 64x64 tile worklist;
//      counted-vmcnt double buffer; relu + bias; top-k candidates ----
__global__ __launch_bounds__(256) void gemm2_kernel(
    const unsigned short* __restrict__ A1c,  // [32][512][1024]
    const unsigned short* __restrict__ V,    // [32][512][1024]
    const unsigned* __restrict__ nv1, const unsigned* __restrict__ nv2,
    const float* __restrict__ bptr,
    unsigned* __restrict__ cand,             // [32*NT][CAP]
    unsigned* __restrict__ cnt,              // [32*NT]
    const unsigned* __restrict__ wl, const unsigned* __restrict__ wcount) {
    __shared__ unsigned short As0[2][64][32];   // [khalf][row][col]
    __shared__ unsigned short Bs0[2][64][32];
    __shared__ unsigned short As1[2][64][32];
    __shared__ unsigned short Bs1[2][64][32];
    __shared__ unsigned lh[NBIN];
    __shared__ unsigned csum[256];
    __shared__ unsigned sel_c, sel_a, tsh, lcnt, zeq;
    int tid = threadIdx.x;
    int wave = tid >> 6, lane = tid & 63;
    int lane15 = lane & 15, quad = lane >> 4;
    unsigned nwork = *wcount;
    float bias = bptr[0];
    // XCD-chunked order: consecutive worklist entries (same batch) stay on
    // the same XCD for L2 reuse of the batch's A/V panels.
    unsigned chunk = gridDim.x >> 3;
    unsigned w0 = (blockIdx.x & 7) * chunk + (blockIdx.x >> 3);

    for (unsigned w = w0; w < nwork; w += gridDim.x) {
        unsigned d = wl[w];
        int b = d >> 6, ty = (d >> 3) & 7, tx = d & 7;
        int m0 = ty * 64, n0 = tx * 64;
        int gblk = b * NT + ty * 8 + tx;
        unsigned nv1v = nv1[b], nv2v = nv2[b];
        const unsigned short* Ab = A1c + (size_t)b * 512 * DC;
        const unsigned short* Bb = V + (size_t)b * 512 * DC;

        for (int i = tid; i < NBIN; i += 256) lh[i] = 0;
        if (tid == 0) { sel_c = 0xFFFFFFFFu; lcnt = 0; zeq = 0; }

        floatx4 zero = {0.f, 0.f, 0.f, 0.f};
        floatx4 acc[4];
#pragma unroll
        for (int i = 0; i < 4; i++) acc[i] = zero;

        auto stage = [&](unsigned short* la, unsigned short* lb, int k0) {
#pragma unroll
            for (int c = 0; c < 2; c++) {
                int cid = c * 256 + tid;   // [0,512)
                int h = cid >> 8, row = (cid >> 2) & 63, col8 = (cid & 3) * 8;
                g2l16(&Ab[(size_t)(m0 + row) * DC + k0 + h * 32 + col8],
                      la + (c * 256 + wave * 64) * 8);
                g2l16(&Bb[(size_t)(n0 + row) * DC + k0 + h * 32 + col8],
                      lb + (c * 256 + wave * 64) * 8);
            }
        };

        stage(&As0[0][0][0], &Bs0[0][0][0], 0);
#pragma unroll
        for (int t = 0; t < DC / 64; t++) {
            const unsigned short* curA = (t & 1) ? &As1[0][0][0] : &As0[0][0][0];
            const unsigned short* curB = (t & 1) ? &Bs1[0][0][0] : &Bs0[0][0][0];
            if (t + 1 < DC / 64) {
                unsigned short* nxtA = (t & 1) ? &As0[0][0][0] : &As1[0][0][0];
                unsigned short* nxtB = (t & 1) ? &Bs0[0][0][0] : &Bs1[0][0][0];
                stage(nxtA, nxtB, (t + 1) * 64);
                asm volatile("s_waitcnt vmcnt(4)" ::: "memory");  // tile t landed
            } else {
                asm volatile("s_waitcnt vmcnt(0)" ::: "memory");
            }
            __builtin_amdgcn_s_barrier();
            CFENCE;
#pragma unroll
            for (int h = 0; h < 2; h++) {
                bf16x8 af, bfr[4];
                af = *reinterpret_cast<const bf16x8*>(
                    curA + h * 2048 + (wave * 16 + lane15) * 32 + quad * 8);
#pragma unroll
                for (int ni = 0; ni < 4; ni++)
                    bfr[ni] = *reinterpret_cast<const bf16x8*>(
                        curB + h * 2048 + (ni * 16 + lane15) * 32 + quad * 8);
#pragma unroll
                for (int ni = 0; ni < 4; ni++)
                    acc[ni] = __builtin_amdgcn_mfma_f32_16x16x32_bf16(
                        af, bfr[ni], acc[ni], 0, 0, 0);
            }
            CFENCE;
            __builtin_amdgcn_s_barrier();
            CFENCE;
        }

        // pass 1: 4096-bin histogram (zero scores privatized)
        unsigned zc = 0;
#pragma unroll
        for (int ni = 0; ni < 4; ni++) {
            int jl = n0 + ni * 16 + lane15;
            int v2 = (unsigned)jl < nv2v;
#pragma unroll
            for (int r = 0; r < 4; r++) {
                int il = m0 + wave * 16 + quad * 4 + r;
                float s = acc[ni][r] + bias;
                if (v2 && (unsigned)il < nv1v) {
                    if (s > 0.f)
                        atomicAdd(&lh[(__float_as_uint(s) | 0x80000000u) >> 20], 1u);
                    else
                        zc++;
                }
            }
        }
        if (zc) atomicAdd(&lh[2048], zc);
        __syncthreads();
        unsigned s16 = 0;
#pragma unroll
        for (int i = 0; i < 16; i++) s16 += lh[tid * 16 + i];
        csum[tid] = s16;
        __syncthreads();
        // parallel suffix scan over 256 chunks
        for (int off = 1; off < 256; off <<= 1) {
            unsigned v = (tid + off < 256) ? csum[tid + off] : 0u;
            __syncthreads();
            csum[tid] += v;
            __syncthreads();
        }
        {   // locate chunk holding the 256th (valid chunks are >=128)
            unsigned above = (tid < 255) ? csum[tid + 1] : 0u;
            if (tid >= 128 && csum[tid] >= KTOP && above < KTOP) {
                sel_c = (unsigned)tid; sel_a = above;
            }
        }
        __syncthreads();
        if (tid == 0) {
            if (sel_c == 0xFFFFFFFFu) {
                tsh = 2048u << 20;          // fewer than k valid: take all
            } else {
                unsigned cum = sel_a, bin = 2048;
                for (int bb = (int)sel_c * 16 + 15; bb >= (int)sel_c * 16; --bb) {
                    unsigned hb = lh[bb];
                    if (cum + hb >= KTOP) { bin = (unsigned)bb; break; }
                    cum += hb;
                }
                tsh = bin << 20;
            }
        }
        __syncthreads();
        // pass 2: emit; exact-T ties gated to <= KTOP
        unsigned T = tsh;
        unsigned base = (unsigned)gblk * CAP;
#pragma unroll
        for (int ni = 0; ni < 4; ni++) {
            int jl = n0 + ni * 16 + lane15;
            int v2 = (unsigned)jl < nv2v;
#pragma unroll
            for (int r = 0; r < 4; r++) {
                int il = m0 + wave * 16 + quad * 4 + r;
                float s = acc[ni][r] + bias;
                s = s > 0.f ? s : 0.f;
                unsigned key = (v2 && (unsigned)il < nv1v)
                                   ? (__float_as_uint(s) | 0x80000000u) : 0u;
                if (key > T) {
                    unsigned p = atomicAdd(&lcnt, 1u);
                    if (p < CAP) cand[base + p] = key;
                } else if (key == T) {
                    unsigned z = atomicAdd(&zeq, 1u);
                    if (z < KTOP) {
                        unsigned p = atomicAdd(&lcnt, 1u);
                        if (p < CAP) cand[base + p] = key;
                    }
                }
            }
        }
        __syncthreads();
        if (tid == 0) cnt[gblk] = lcnt < CAP ? lcnt : CAP;
        __syncthreads();
    }
}

// ---- final: per batch, EXACT top-256 via 3-pass LDS radix select ----
__global__ __launch_bounds__(1024) void final_kernel(
    const unsigned* __restrict__ cand, const unsigned* __restrict__ cnt,
    float* __restrict__ out) {
    __shared__ unsigned buf[FBUF];     // 64 KB
    __shared__ unsigned h[NBIN];       // 16 KB
    __shared__ unsigned ss[256];
    __shared__ unsigned scnt_s[NT], off_s[NT];
    __shared__ unsigned ntot_s, sel_c, sel_a, B_s, R_s, mcount;
    __shared__ int have_s;
    __shared__ unsigned srt[256];
    int b = blockIdx.x, tid = threadIdx.x;
    int wv = tid >> 6, ln = tid & 63;

    if (tid < NT) {
        unsigned c = cnt[b * NT + tid];
        scnt_s[tid] = c < CAP ? c : CAP;
    }
    __syncthreads();
    if (tid == 0) {
        unsigned o = 0;
        for (int i = 0; i < NT; i++) {
            unsigned c = scnt_s[i];
            if (o + c > FBUF) c = (o < FBUF) ? FBUF - o : 0;
            scnt_s[i] = c;
            off_s[i] = o;
            o += c;
        }
        ntot_s = o;
        have_s = 1;
    }
    __syncthreads();
    // wave-parallel staging: wave wv handles segments wv, wv+16, ...
    for (int s = wv; s < NT; s += 16) {
        unsigned c = scnt_s[s], o = off_s[s];
        const unsigned* p = cand + (size_t)(b * NT + s) * CAP;
        for (unsigned i = ln; i < c; i += 64) buf[o + i] = p[i];
    }
    __syncthreads();
    unsigned n = ntot_s;

    unsigned Kr = KTOP;
    unsigned pfx = 0;
    unsigned kth = 0;
    for (int pass = 0; pass < 3; pass++) {
        int bins = (pass < 2) ? NBIN : 256;
        int shift = (pass == 0) ? 20 : (pass == 1) ? 8 : 0;
        int nch = bins >> 4;
        for (int i = tid; i < bins; i += 1024) h[i] = 0;
        __syncthreads();
        for (unsigned i = tid; i < n; i += 1024) {
            unsigned k = buf[i];
            bool ok = (pass == 0) ||
                      (pass == 1 && (k >> 20) == pfx) ||
                      (pass == 2 && (k >> 8) == pfx);
            if (ok) atomicAdd(&h[(k >> shift) & (bins - 1)], 1u);
        }
        __syncthreads();
        if (tid < nch) {
            unsigned s = 0;
#pragma unroll
            for (int i = 0; i < 16; i++) s += h[tid * 16 + i];
            ss[tid] = s;
        }
        __syncthreads();
        for (int off = 1; off < nch; off <<= 1) {
            unsigned v = 0;
            if (tid < nch && tid + (unsigned)off < (unsigned)nch) v = ss[tid + off];
            __syncthreads();
            if (tid < nch) ss[tid] += v;
            __syncthreads();
        }
        if (pass == 0) {
            if (tid == 0) have_s = (ss[0] >= KTOP);
            __syncthreads();
            if (!have_s) break;
        }
        if (tid < nch) {
            unsigned above = (tid + 1 < (unsigned)nch) ? ss[tid + 1] : 0u;
            if (above < Kr && ss[tid] >= Kr) { sel_c = tid; sel_a = above; }
        }
        __syncthreads();
        if (tid == 0) {
            unsigned cum = sel_a;
            for (int bb = (int)sel_c * 16 + 15; bb >= (int)sel_c * 16; --bb) {
                unsigned hb = h[bb];
                if (cum + hb >= Kr) { B_s = (unsigned)bb; R_s = Kr - cum; break; }
                cum += hb;
            }
        }
        __syncthreads();
        unsigned Bv = B_s;
        Kr = R_s;
        if (pass == 0) pfx = Bv;
        else if (pass == 1) pfx = (pfx << 12) | Bv;
        else kth = (pfx << 8) | Bv;
        __syncthreads();
    }

    if (tid == 0) mcount = 0;
    __syncthreads();
    int have = have_s;
    unsigned lim = have ? kth : 0u;
    for (unsigned i = tid; i < n; i += 1024) {
        unsigned k = buf[i];
        if (k > lim) {
            unsigned p = atomicAdd(&mcount, 1u);
            if (p < 256) srt[p] = k;
        }
    }
    __syncthreads();
    unsigned m = mcount;
    if (tid < 256 && tid >= (int)m) srt[tid] = have ? kth : 0u;
    for (int k2 = 2; k2 <= 256; k2 <<= 1) {
        for (int j2 = k2 >> 1; j2 > 0; j2 >>= 1) {
            __syncthreads();
            if (tid < 256) {
                int ixj = tid ^ j2;
                if (ixj > tid) {
                    unsigned a = srt[tid], c = srt[ixj];
                    bool up = (tid & k2) == 0;
                    if (up ? (a < c) : (a > c)) { srt[tid] = c; srt[ixj] = a; }
                }
            }
        }
    }
    __syncthreads();
    if (tid < 256) {
        unsigned nval = have ? KTOP : (m < KTOP ? m : KTOP);
        float v;
        if ((unsigned)tid < nval) v = decode_key(srt[tid]);
        else v = (nval > 0) ? decode_key(srt[nval - 1]) : -__builtin_inff();
        out[b * KTOP + tid] = v;
    }
}

// ---------------- launch ----------------
extern "C" void kernel_launch(void* const* d_in, const int* in_sizes, int n_in,
                              void* d_out, int out_size, void* d_ws, size_t ws_size,
                              hipStream_t stream) {
    const float* in1   = (const float*)d_in[0];   // [512,32,1024]
    const float* in2   = (const float*)d_in[1];   // [512,32,1024]
    const int*   mask1 = (const int*)d_in[2];     // [512,32]
    const int*   mask2 = (const int*)d_in[3];     // [512,32]
    const float* W     = (const float*)d_in[4];   // [1024,1024]
    const float* bias  = (const float*)d_in[5];   // [1]
    float* out = (float*)d_out;

    char* ws = (char*)d_ws;
    size_t off = 0;
    const size_t nElem = (size_t)512 * BC * DC;
    unsigned short* A1c = (unsigned short*)(ws + off); off += nElem * 2;      // 32 MB
    unsigned short* A2c = (unsigned short*)(ws + off); off += nElem * 2;      // 32 MB
    unsigned short* Wb  = (unsigned short*)(ws + off); off += (size_t)DC * DC * 2; // 2 MB
    unsigned short* V   = (unsigned short*)(ws + off); off += nElem * 2;      // 32 MB
    unsigned* cand = (unsigned*)(ws + off); off += (size_t)BC * NT * CAP * 4; // 4 MB
    unsigned* cnt  = (unsigned*)(ws + off); off += (size_t)BC * NT * 4;
    int* idx1 = (int*)(ws + off); off += (size_t)BC * 512 * 4;
    int* idx2 = (int*)(ws + off); off += (size_t)BC * 512 * 4;
    unsigned* nv1 = (unsigned*)(ws + off); off += BC * 4;
    unsigned* nv2 = (unsigned*)(ws + off); off += BC * 4;
    unsigned* wl  = (unsigned*)(ws + off); off += 2048 * 4;
    unsigned* wcount = (unsigned*)(ws + off); off += 4;

    scan_kernel<<<BC, 512, 0, stream>>>(mask1, mask2, idx1, idx2, nv1, nv2, cnt);
    wl_kernel<<<1, 256, 0, stream>>>(nv1, nv2, wl, wcount);
    prep_kernel<<<2 * 16384 + 1024, 256, 0, stream>>>(
        in1, in2, W, idx1, idx2, nv1, nv2, A1c, A2c, Wb);
    gemm1_kernel<<<dim3(128, 8), 256, 0, stream>>>(A2c, Wb, V, nv2);
    gemm2_kernel<<<768, 256, 0, stream>>>(A1c, V, nv1, nv2, bias, cand, cnt,
                                          wl, wcount);
    final_kernel<<<BC, 1024, 0, stream>>>(cand, cnt, out);
}